// Round 1
// baseline (449.568 us; speedup 1.0000x reference)
//
#include <hip/hip_runtime.h>
#include <hip/hip_bf16.h>
#include <stdint.h>

#define IN_C 128
#define HID_C 128
#define OUT_C 64

typedef _Float16 h8 __attribute__((ext_vector_type(8)));
typedef _Float16 h2 __attribute__((ext_vector_type(2)));
typedef float f4 __attribute__((ext_vector_type(4)));

__device__ inline float h2lo(unsigned v){ h2 t = __builtin_bit_cast(h2, v); return (float)t[0]; }
__device__ inline float h2hi(unsigned v){ h2 t = __builtin_bit_cast(h2, v); return (float)t[1]; }
__device__ inline unsigned packh2(float a, float b){ h2 t; t[0]=(_Float16)a; t[1]=(_Float16)b; return __builtin_bit_cast(unsigned, t); }

// ---------------- CSR build ----------------
__global__ void k_count(const int* __restrict__ dst, int E, int* __restrict__ cnt){
    int g = blockIdx.x*256 + threadIdx.x;
    if (g < E) atomicAdd(&cnt[dst[g]], 1);
}

__global__ void k_scanA(const int* __restrict__ cnt, int* __restrict__ tmp, int* __restrict__ bsum, int n){
    __shared__ int s[256];
    int t = threadIdx.x, g = blockIdx.x*256 + t;
    int v = (g < n) ? cnt[g] : 0;
    s[t] = v; __syncthreads();
    for (int off = 1; off < 256; off <<= 1){
        int a = (t >= off) ? s[t-off] : 0;
        __syncthreads();
        s[t] += a;
        __syncthreads();
    }
    int excl = (t == 0) ? 0 : s[t-1];
    if (g < n) tmp[g] = excl;
    if (t == 255) bsum[blockIdx.x] = s[255];
}

__global__ void k_scanB(int* __restrict__ bsum, int nb){
    __shared__ int s[1024];
    int t = threadIdx.x;
    int v = (t < nb) ? bsum[t] : 0;
    s[t] = v; __syncthreads();
    for (int off = 1; off < 1024; off <<= 1){
        int a = (t >= off) ? s[t-off] : 0;
        __syncthreads();
        s[t] += a;
        __syncthreads();
    }
    int excl = (t == 0) ? 0 : s[t-1];
    if (t < nb) bsum[t] = excl;
}

__global__ void k_scanC(const int* __restrict__ tmp, const int* __restrict__ bsum,
                        int* __restrict__ row_start, int* __restrict__ woff, int n, int E){
    int g = blockIdx.x*256 + threadIdx.x;
    if (g < n){
        int v = tmp[g] + bsum[blockIdx.x];
        row_start[g] = v;
        woff[g] = v;
    }
    if (g == 0) row_start[n] = E;
}

__global__ void k_fill(const int* __restrict__ src, const int* __restrict__ dst, int E,
                       int* __restrict__ woff, int* __restrict__ csr){
    int g = blockIdx.x*256 + threadIdx.x;
    if (g < E){
        int d = dst[g];
        int pos = atomicAdd(&woff[d], 1);
        csr[pos] = src[g];
    }
}

// ---------------- fp32 -> fp16 conversion ----------------
__global__ void k_cvt(const float* __restrict__ x, h8* __restrict__ xh, int n8){
    int g = blockIdx.x*256 + threadIdx.x;
    if (g < n8){
        const f4* xp = (const f4*)(x + (size_t)g*8);
        f4 a = xp[0], b = xp[1];
        h8 o;
        o[0]=(_Float16)a[0]; o[1]=(_Float16)a[1]; o[2]=(_Float16)a[2]; o[3]=(_Float16)a[3];
        o[4]=(_Float16)b[0]; o[5]=(_Float16)b[1]; o[6]=(_Float16)b[2]; o[7]=(_Float16)b[3];
        xh[g] = o;
    }
}

// ---------------- weight packing into MFMA B-fragment layout ----------------
// consumed as Bp[(kt*NJT + jt)*64 + lane] -> h8 with element r = W[kt*32 + (lane>>4)*8 + r][jt*16 + (lane&15)]
__device__ inline void pack_one(const float* __restrict__ W, int C, _Float16* __restrict__ outp, int tid){
    int l = tid & 63;
    int f = tid >> 6;
    int NJT = C / 16;
    int kt = f / NJT;
    int jt = f - kt*NJT;
    int kbase = kt*32 + (l >> 4)*8;
    int col   = jt*16 + (l & 15);
    h8 o;
    #pragma unroll
    for (int r = 0; r < 8; ++r) o[r] = (_Float16)W[(kbase + r)*C + col];
    ((h8*)outp)[f*64 + l] = o;
}

__global__ void k_pack(const float* __restrict__ Wl1, const float* __restrict__ Wr1,
                       const float* __restrict__ Wl2, const float* __restrict__ Wr2,
                       _Float16* __restrict__ wl1p, _Float16* __restrict__ wr1p,
                       _Float16* __restrict__ wl2p, _Float16* __restrict__ wr2p){
    int tid = blockIdx.x*256 + threadIdx.x;
    if (tid < 2048)        pack_one(Wl1, 128, wl1p, tid);
    else if (tid < 4096)   pack_one(Wr1, 128, wr1p, tid - 2048);
    else if (tid < 5120)   pack_one(Wl2,  64, wl2p, tid - 4096);
    else if (tid < 6144)   pack_one(Wr2,  64, wr2p, tid - 5120);
}

// ---------------- aggregation 1: mean of xh (128 f16 = 64 u32) per node ----------------
__global__ void k_agg1(const int* __restrict__ row_start, const int* __restrict__ csr,
                       const unsigned* __restrict__ xh32, unsigned* __restrict__ mh32, int n){
    int wave = (int)((blockIdx.x*(unsigned)blockDim.x + threadIdx.x) >> 6);
    int lane = threadIdx.x & 63;
    if (wave >= n) return;
    int base = row_start[wave], end = row_start[wave+1];
    int deg = end - base;
    float a0=0,a1=0,b0=0,b1=0,c0=0,c1=0,d0=0,d1=0;
    int i = base;
    for (; i + 4 <= end; i += 4){
        int e0 = csr[i], e1 = csr[i+1], e2 = csr[i+2], e3 = csr[i+3];
        unsigned v0 = xh32[(size_t)e0*64 + lane];
        unsigned v1 = xh32[(size_t)e1*64 + lane];
        unsigned v2 = xh32[(size_t)e2*64 + lane];
        unsigned v3 = xh32[(size_t)e3*64 + lane];
        a0 += h2lo(v0); a1 += h2hi(v0);
        b0 += h2lo(v1); b1 += h2hi(v1);
        c0 += h2lo(v2); c1 += h2hi(v2);
        d0 += h2lo(v3); d1 += h2hi(v3);
    }
    for (; i < end; ++i){
        int e = csr[i];
        unsigned v = xh32[(size_t)e*64 + lane];
        a0 += h2lo(v); a1 += h2hi(v);
    }
    float s0 = (a0 + b0) + (c0 + d0);
    float s1 = (a1 + b1) + (c1 + d1);
    float sc = 1.0f / (float)max(deg, 1);
    mh32[(size_t)wave*64 + lane] = packh2(s0*sc, s1*sc);
}

// ---------------- aggregation 2: mean of ph (64 f16 = 32 u32) per node ----------------
__global__ void k_agg2(const int* __restrict__ row_start, const int* __restrict__ csr,
                       const unsigned* __restrict__ ph32, unsigned* __restrict__ mp32, int n){
    int wave = (int)((blockIdx.x*(unsigned)blockDim.x + threadIdx.x) >> 6);
    int lane = threadIdx.x & 63;
    if (wave >= n) return;
    int c = lane & 31, h = lane >> 5;
    int base = row_start[wave], end = row_start[wave+1];
    int deg = end - base;
    float a0=0,a1=0,b0=0,b1=0;
    int i = base + h;
    for (; i + 2 < end; i += 4){
        int e0 = csr[i], e1 = csr[i+2];
        unsigned v0 = ph32[(size_t)e0*32 + c];
        unsigned v1 = ph32[(size_t)e1*32 + c];
        a0 += h2lo(v0); a1 += h2hi(v0);
        b0 += h2lo(v1); b1 += h2hi(v1);
    }
    for (; i < end; i += 2){
        int e = csr[i];
        unsigned v = ph32[(size_t)e*32 + c];
        a0 += h2lo(v); a1 += h2hi(v);
    }
    a0 += b0; a1 += b1;
    a0 += __shfl_xor(a0, 32);
    a1 += __shfl_xor(a1, 32);
    if (h == 0){
        float sc = 1.0f / (float)max(deg, 1);
        mp32[(size_t)wave*32 + c] = packh2(a0*sc, a1*sc);
    }
}

// ---------------- GEMM 1: H = relu(M1 @ Wl1 + b1 + X @ Wr1), all [M x 128] ----------------
__global__ __launch_bounds__(256) void k_gemm1(
    const _Float16* __restrict__ A0, const _Float16* __restrict__ A1,
    const h8* __restrict__ B0, const h8* __restrict__ B1,
    const float* __restrict__ bias, _Float16* __restrict__ H, int M)
{
    int wid = threadIdx.x >> 6, lane = threadIdx.x & 63;
    int m0 = (blockIdx.x*4 + wid) * 64;
    if (m0 >= M) return;
    int rl = lane & 15, kg = lane >> 4;
    f4 acc[4][8];
    #pragma unroll
    for (int s = 0; s < 4; ++s)
        #pragma unroll
        for (int j = 0; j < 8; ++j) acc[s][j] = (f4)0.0f;

    #pragma unroll
    for (int ph = 0; ph < 2; ++ph){
        const _Float16* A = ph ? A1 : A0;
        const h8* B = ph ? B1 : B0;
        #pragma unroll
        for (int kt = 0; kt < 4; ++kt){
            h8 a[4];
            #pragma unroll
            for (int s = 0; s < 4; ++s){
                int row = m0 + s*16 + rl;
                row = min(row, M-1);
                a[s] = *(const h8*)(A + (size_t)row*128 + kt*32 + kg*8);
            }
            #pragma unroll
            for (int j = 0; j < 8; ++j){
                h8 b = B[(kt*8 + j)*64 + lane];
                #pragma unroll
                for (int s = 0; s < 4; ++s)
                    acc[s][j] = __builtin_amdgcn_mfma_f32_16x16x32_f16(a[s], b, acc[s][j], 0, 0, 0);
            }
        }
    }
    #pragma unroll
    for (int j = 0; j < 8; ++j){
        int col = j*16 + rl;
        float bb = bias[col];
        #pragma unroll
        for (int s = 0; s < 4; ++s){
            #pragma unroll
            for (int r = 0; r < 4; ++r){
                int row = m0 + s*16 + kg*4 + r;
                float v = acc[s][j][r] + bb;
                v = v > 0.f ? v : 0.f;
                if (row < M) H[(size_t)row*128 + col] = (_Float16)v;
            }
        }
    }
}

// ---------------- GEMM 2a: P = H @ Wl2, [M x 64] ----------------
__global__ __launch_bounds__(256) void k_gemm2a(
    const _Float16* __restrict__ Hh, const h8* __restrict__ Bp,
    _Float16* __restrict__ P, int M)
{
    int wid = threadIdx.x >> 6, lane = threadIdx.x & 63;
    int m0 = (blockIdx.x*4 + wid) * 64;
    if (m0 >= M) return;
    int rl = lane & 15, kg = lane >> 4;
    f4 acc[4][4];
    #pragma unroll
    for (int s = 0; s < 4; ++s)
        #pragma unroll
        for (int j = 0; j < 4; ++j) acc[s][j] = (f4)0.0f;

    #pragma unroll
    for (int kt = 0; kt < 4; ++kt){
        h8 a[4];
        #pragma unroll
        for (int s = 0; s < 4; ++s){
            int row = m0 + s*16 + rl;
            row = min(row, M-1);
            a[s] = *(const h8*)(Hh + (size_t)row*128 + kt*32 + kg*8);
        }
        #pragma unroll
        for (int j = 0; j < 4; ++j){
            h8 b = Bp[(kt*4 + j)*64 + lane];
            #pragma unroll
            for (int s = 0; s < 4; ++s)
                acc[s][j] = __builtin_amdgcn_mfma_f32_16x16x32_f16(a[s], b, acc[s][j], 0, 0, 0);
        }
    }
    #pragma unroll
    for (int j = 0; j < 4; ++j){
        int col = j*16 + rl;
        #pragma unroll
        for (int s = 0; s < 4; ++s){
            #pragma unroll
            for (int r = 0; r < 4; ++r){
                int row = m0 + s*16 + kg*4 + r;
                if (row < M) P[(size_t)row*64 + col] = (_Float16)acc[s][j][r];
            }
        }
    }
}

// ---------------- GEMM 2b: OUT = H @ Wr2 + b2 + MP, [M x 64] f32 out ----------------
__global__ __launch_bounds__(256) void k_gemm2b(
    const _Float16* __restrict__ Hh, const h8* __restrict__ Bp,
    const float* __restrict__ bias, const _Float16* __restrict__ MP,
    float* __restrict__ OUT, int M)
{
    int wid = threadIdx.x >> 6, lane = threadIdx.x & 63;
    int m0 = (blockIdx.x*4 + wid) * 64;
    if (m0 >= M) return;
    int rl = lane & 15, kg = lane >> 4;
    f4 acc[4][4];
    #pragma unroll
    for (int s = 0; s < 4; ++s)
        #pragma unroll
        for (int j = 0; j < 4; ++j) acc[s][j] = (f4)0.0f;

    #pragma unroll
    for (int kt = 0; kt < 4; ++kt){
        h8 a[4];
        #pragma unroll
        for (int s = 0; s < 4; ++s){
            int row = m0 + s*16 + rl;
            row = min(row, M-1);
            a[s] = *(const h8*)(Hh + (size_t)row*128 + kt*32 + kg*8);
        }
        #pragma unroll
        for (int j = 0; j < 4; ++j){
            h8 b = Bp[(kt*4 + j)*64 + lane];
            #pragma unroll
            for (int s = 0; s < 4; ++s)
                acc[s][j] = __builtin_amdgcn_mfma_f32_16x16x32_f16(a[s], b, acc[s][j], 0, 0, 0);
        }
    }
    #pragma unroll
    for (int j = 0; j < 4; ++j){
        int col = j*16 + rl;
        float bb = bias[col];
        #pragma unroll
        for (int s = 0; s < 4; ++s){
            #pragma unroll
            for (int r = 0; r < 4; ++r){
                int row = m0 + s*16 + kg*4 + r;
                if (row < M){
                    float v = acc[s][j][r] + bb + (float)MP[(size_t)row*64 + col];
                    OUT[(size_t)row*64 + col] = v;
                }
            }
        }
    }
}

extern "C" void kernel_launch(void* const* d_in, const int* in_sizes, int n_in,
                              void* d_out, int out_size, void* d_ws, size_t ws_size,
                              hipStream_t stream) {
    const float* x   = (const float*)d_in[0];
    const int*   ei  = (const int*)d_in[1];
    const float* Wl1 = (const float*)d_in[2];
    const float* bl1 = (const float*)d_in[3];
    const float* Wr1 = (const float*)d_in[4];
    const float* Wl2 = (const float*)d_in[5];
    const float* bl2 = (const float*)d_in[6];
    const float* Wr2 = (const float*)d_in[7];

    const int N = in_sizes[0] / IN_C;
    const int E = in_sizes[1] / 2;
    const int* src = ei;
    const int* dst = ei + E;

    // workspace carve (256B aligned)
    char* w = (char*)d_ws;
    size_t off = 0;
    auto alloc = [&](size_t bytes) -> char* {
        char* p = w + off;
        off = (off + bytes + 255) & ~(size_t)255;
        return p;
    };
    int* cnt        = (int*)alloc((size_t)N*4);
    int* row_start  = (int*)alloc((size_t)(N+1)*4);
    int* woff       = (int*)alloc((size_t)N*4);
    int* bsum       = (int*)alloc(4096);
    int* tmp        = (int*)alloc((size_t)N*4);
    int* csr        = (int*)alloc((size_t)E*4);
    _Float16* xh    = (_Float16*)alloc((size_t)N*IN_C*2);
    _Float16* m1h   = (_Float16*)alloc((size_t)N*IN_C*2);
    _Float16* hh    = (_Float16*)alloc((size_t)N*HID_C*2);
    _Float16* ph    = (_Float16*)alloc((size_t)N*OUT_C*2);
    _Float16* mph   = (_Float16*)alloc((size_t)N*OUT_C*2);
    _Float16* wl1p  = (_Float16*)alloc(4*8*64*8*2);
    _Float16* wr1p  = (_Float16*)alloc(4*8*64*8*2);
    _Float16* wl2p  = (_Float16*)alloc(4*4*64*8*2);
    _Float16* wr2p  = (_Float16*)alloc(4*4*64*8*2);

    const int NB  = (N + 255) / 256;
    const int EB  = (E + 255) / 256;

    hipMemsetAsync(cnt, 0, (size_t)N*4, stream);

    k_count<<<EB, 256, 0, stream>>>(dst, E, cnt);
    k_scanA<<<NB, 256, 0, stream>>>(cnt, tmp, bsum, N);
    k_scanB<<<1, 1024, 0, stream>>>(bsum, NB);
    k_scanC<<<NB, 256, 0, stream>>>(tmp, bsum, row_start, woff, N, E);
    k_fill<<<EB, 256, 0, stream>>>(src, dst, E, woff, csr);

    const int n8 = N*IN_C/8;
    k_cvt<<<(n8 + 255)/256, 256, 0, stream>>>(x, (h8*)xh, n8);
    k_pack<<<24, 256, 0, stream>>>(Wl1, Wr1, Wl2, Wr2, wl1p, wr1p, wl2p, wr2p);

    k_agg1<<<(N + 3)/4, 256, 0, stream>>>(row_start, csr, (const unsigned*)xh, (unsigned*)m1h, N);

    const int GB = (N + 255)/256;   // 64 rows per wave, 4 waves per block
    k_gemm1<<<GB, 256, 0, stream>>>(m1h, xh, (const h8*)wl1p, (const h8*)wr1p, bl1, hh, N);
    k_gemm2a<<<GB, 256, 0, stream>>>(hh, (const h8*)wl2p, ph, N);
    k_agg2<<<(N + 3)/4, 256, 0, stream>>>(row_start, csr, (const unsigned*)ph, (unsigned*)mph, N);
    k_gemm2b<<<GB, 256, 0, stream>>>(hh, (const h8*)wr2p, bl2, mph, (float*)d_out, N);
}

// Round 2
// 291.864 us; speedup vs baseline: 1.5403x; 1.5403x over previous
//
#include <hip/hip_runtime.h>
#include <hip/hip_bf16.h>
#include <stdint.h>

#define IN_C 128
#define HID_C 128
#define OUT_C 64

#define NBUCK 256
#define BSH 9
#define EPB 4096

typedef _Float16 h8 __attribute__((ext_vector_type(8)));
typedef _Float16 h2 __attribute__((ext_vector_type(2)));
typedef float f4 __attribute__((ext_vector_type(4)));

__device__ inline float h2lo(unsigned v){ h2 t = __builtin_bit_cast(h2, v); return (float)t[0]; }
__device__ inline float h2hi(unsigned v){ h2 t = __builtin_bit_cast(h2, v); return (float)t[1]; }
__device__ inline unsigned packh2(float a, float b){ h2 t; t[0]=(_Float16)a; t[1]=(_Float16)b; return __builtin_bit_cast(unsigned, t); }

// ---------------- CSR build: atomic-free counting sort ----------------
// pass 0: per-block LDS histogram over 256 coarse buckets (dst>>9), transposed out
__global__ __launch_bounds__(256) void k_hist(const int* __restrict__ dst, int E,
                                              int* __restrict__ histT, int NBLK){
    __shared__ int h[NBUCK];
    int t = threadIdx.x;
    h[t] = 0; __syncthreads();
    int e0 = blockIdx.x*EPB, e1 = min(E, e0 + EPB);
    for (int e = e0 + t; e < e1; e += 256) atomicAdd(&h[((unsigned)dst[e]) >> BSH], 1);
    __syncthreads();
    histT[t*NBLK + blockIdx.x] = h[t];
}

__global__ void k_scanA(const int* __restrict__ cnt, int* __restrict__ tmp, int* __restrict__ bsum, int n){
    __shared__ int s[256];
    int t = threadIdx.x, g = blockIdx.x*256 + t;
    int v = (g < n) ? cnt[g] : 0;
    s[t] = v; __syncthreads();
    for (int off = 1; off < 256; off <<= 1){
        int a = (t >= off) ? s[t-off] : 0;
        __syncthreads();
        s[t] += a;
        __syncthreads();
    }
    int excl = (t == 0) ? 0 : s[t-1];
    if (g < n) tmp[g] = excl;
    if (t == 255) bsum[blockIdx.x] = s[255];
}

__global__ void k_scanB(int* __restrict__ bsum, int nb){
    __shared__ int s[1024];
    int t = threadIdx.x;
    int v = (t < nb) ? bsum[t] : 0;
    s[t] = v; __syncthreads();
    for (int off = 1; off < 1024; off <<= 1){
        int a = (t >= off) ? s[t-off] : 0;
        __syncthreads();
        s[t] += a;
        __syncthreads();
    }
    int excl = (t == 0) ? 0 : s[t-1];
    if (t < nb) bsum[t] = excl;
}

__global__ void k_scanCg(const int* __restrict__ tmp, const int* __restrict__ bsum,
                         int* __restrict__ S, int n){
    int g = blockIdx.x*256 + threadIdx.x;
    if (g < n) S[g] = tmp[g] + bsum[blockIdx.x];
}

// pass 1: scatter edges into bucket-grouped array; block-exclusive contiguous runs (no global atomics)
__global__ __launch_bounds__(256) void k_scatter(const int* __restrict__ src, const int* __restrict__ dst,
                                                 int E, const int* __restrict__ S, int NBLK,
                                                 unsigned* __restrict__ sorted){
    __shared__ int off[NBUCK];
    int t = threadIdx.x;
    off[t] = S[t*NBLK + blockIdx.x];
    __syncthreads();
    int e0 = blockIdx.x*EPB, e1 = min(E, e0 + EPB);
    for (int e = e0 + t; e < e1; e += 256){
        int d = dst[e];
        int b = ((unsigned)d) >> BSH;
        int p = atomicAdd(&off[b], 1);
        sorted[p] = (unsigned)src[e] | (((unsigned)(d & ((1<<BSH)-1))) << 17);
    }
}

// pass 2: per bucket (512 node ids, contiguous csr window): LDS count -> scan -> row_start + csr fill
__global__ __launch_bounds__(512) void k_csr(const unsigned* __restrict__ sorted, const int* __restrict__ S,
                                             int NBLK, int E, int N,
                                             int* __restrict__ csr, int* __restrict__ row_start){
    __shared__ int cnt[512];
    __shared__ int sc[512];
    int b = blockIdx.x, t = threadIdx.x;
    int bs = S[b*NBLK];
    int be = (b == NBUCK-1) ? E : S[(b+1)*NBLK];
    cnt[t] = 0; __syncthreads();
    for (int e = bs + t; e < be; e += 512) atomicAdd(&cnt[sorted[e] >> 17], 1);
    __syncthreads();
    sc[t] = cnt[t]; __syncthreads();
    for (int off = 1; off < 512; off <<= 1){
        int a = (t >= off) ? sc[t-off] : 0;
        __syncthreads();
        sc[t] += a;
        __syncthreads();
    }
    int excl = sc[t] - cnt[t];
    int nid = (b << BSH) + t;
    if (nid < N) row_start[nid] = bs + excl;
    if (t == 0 && b == (N >> BSH)) row_start[N] = E;
    __syncthreads();
    cnt[t] = excl;       // reuse as running write offset (local)
    __syncthreads();
    for (int e = bs + t; e < be; e += 512){
        unsigned v = sorted[e];
        int dl = v >> 17;
        int p = atomicAdd(&cnt[dl], 1);
        csr[bs + p] = (int)(v & 0x1FFFFu);
    }
}

// ---------------- fp32 -> fp16 conversion ----------------
__global__ void k_cvt(const float* __restrict__ x, h8* __restrict__ xh, int n8){
    int g = blockIdx.x*256 + threadIdx.x;
    if (g < n8){
        const f4* xp = (const f4*)(x + (size_t)g*8);
        f4 a = xp[0], b = xp[1];
        h8 o;
        o[0]=(_Float16)a[0]; o[1]=(_Float16)a[1]; o[2]=(_Float16)a[2]; o[3]=(_Float16)a[3];
        o[4]=(_Float16)b[0]; o[5]=(_Float16)b[1]; o[6]=(_Float16)b[2]; o[7]=(_Float16)b[3];
        xh[g] = o;
    }
}

// ---------------- weight packing into MFMA B-fragment layout ----------------
__device__ inline void pack_one(const float* __restrict__ W, int C, _Float16* __restrict__ outp, int tid){
    int l = tid & 63;
    int f = tid >> 6;
    int NJT = C / 16;
    int kt = f / NJT;
    int jt = f - kt*NJT;
    int kbase = kt*32 + (l >> 4)*8;
    int col   = jt*16 + (l & 15);
    h8 o;
    #pragma unroll
    for (int r = 0; r < 8; ++r) o[r] = (_Float16)W[(kbase + r)*C + col];
    ((h8*)outp)[f*64 + l] = o;
}

__global__ void k_pack(const float* __restrict__ Wl1, const float* __restrict__ Wr1,
                       const float* __restrict__ Wl2, const float* __restrict__ Wr2,
                       _Float16* __restrict__ wl1p, _Float16* __restrict__ wr1p,
                       _Float16* __restrict__ wl2p, _Float16* __restrict__ wr2p){
    int tid = blockIdx.x*256 + threadIdx.x;
    if (tid < 2048)        pack_one(Wl1, 128, wl1p, tid);
    else if (tid < 4096)   pack_one(Wr1, 128, wr1p, tid - 2048);
    else if (tid < 5120)   pack_one(Wl2,  64, wl2p, tid - 4096);
    else if (tid < 6144)   pack_one(Wr2,  64, wr2p, tid - 5120);
}

// ---------------- aggregation 1: mean of xh (128 f16 = 64 u32) per node ----------------
__global__ void k_agg1(const int* __restrict__ row_start, const int* __restrict__ csr,
                       const unsigned* __restrict__ xh32, unsigned* __restrict__ mh32, int n){
    int wave = (int)((blockIdx.x*(unsigned)blockDim.x + threadIdx.x) >> 6);
    int lane = threadIdx.x & 63;
    if (wave >= n) return;
    int base = row_start[wave], end = row_start[wave+1];
    int deg = end - base;
    float a0=0,a1=0,b0=0,b1=0,c0=0,c1=0,d0=0,d1=0;
    int i = base;
    for (; i + 4 <= end; i += 4){
        int e0 = csr[i], e1 = csr[i+1], e2 = csr[i+2], e3 = csr[i+3];
        unsigned v0 = xh32[(size_t)e0*64 + lane];
        unsigned v1 = xh32[(size_t)e1*64 + lane];
        unsigned v2 = xh32[(size_t)e2*64 + lane];
        unsigned v3 = xh32[(size_t)e3*64 + lane];
        a0 += h2lo(v0); a1 += h2hi(v0);
        b0 += h2lo(v1); b1 += h2hi(v1);
        c0 += h2lo(v2); c1 += h2hi(v2);
        d0 += h2lo(v3); d1 += h2hi(v3);
    }
    for (; i < end; ++i){
        int e = csr[i];
        unsigned v = xh32[(size_t)e*64 + lane];
        a0 += h2lo(v); a1 += h2hi(v);
    }
    float s0 = (a0 + b0) + (c0 + d0);
    float s1 = (a1 + b1) + (c1 + d1);
    float sc = 1.0f / (float)max(deg, 1);
    mh32[(size_t)wave*64 + lane] = packh2(s0*sc, s1*sc);
}

// ---------------- aggregation 2: mean of ph (64 f16 = 32 u32) per node ----------------
__global__ void k_agg2(const int* __restrict__ row_start, const int* __restrict__ csr,
                       const unsigned* __restrict__ ph32, unsigned* __restrict__ mp32, int n){
    int wave = (int)((blockIdx.x*(unsigned)blockDim.x + threadIdx.x) >> 6);
    int lane = threadIdx.x & 63;
    if (wave >= n) return;
    int c = lane & 31, h = lane >> 5;
    int base = row_start[wave], end = row_start[wave+1];
    int deg = end - base;
    float a0=0,a1=0,b0=0,b1=0;
    int i = base + h;
    for (; i + 2 < end; i += 4){
        int e0 = csr[i], e1 = csr[i+2];
        unsigned v0 = ph32[(size_t)e0*32 + c];
        unsigned v1 = ph32[(size_t)e1*32 + c];
        a0 += h2lo(v0); a1 += h2hi(v0);
        b0 += h2lo(v1); b1 += h2hi(v1);
    }
    for (; i < end; i += 2){
        int e = csr[i];
        unsigned v = ph32[(size_t)e*32 + c];
        a0 += h2lo(v); a1 += h2hi(v);
    }
    a0 += b0; a1 += b1;
    a0 += __shfl_xor(a0, 32);
    a1 += __shfl_xor(a1, 32);
    if (h == 0){
        float sc = 1.0f / (float)max(deg, 1);
        mp32[(size_t)wave*32 + c] = packh2(a0*sc, a1*sc);
    }
}

// ---------------- GEMM 1: H = relu(M1 @ Wl1 + b1 + X @ Wr1), all [M x 128] ----------------
__global__ __launch_bounds__(256) void k_gemm1(
    const _Float16* __restrict__ A0, const _Float16* __restrict__ A1,
    const h8* __restrict__ B0, const h8* __restrict__ B1,
    const float* __restrict__ bias, _Float16* __restrict__ H, int M)
{
    int wid = threadIdx.x >> 6, lane = threadIdx.x & 63;
    int m0 = (blockIdx.x*4 + wid) * 64;
    if (m0 >= M) return;
    int rl = lane & 15, kg = lane >> 4;
    f4 acc[4][8];
    #pragma unroll
    for (int s = 0; s < 4; ++s)
        #pragma unroll
        for (int j = 0; j < 8; ++j) acc[s][j] = (f4)0.0f;

    #pragma unroll
    for (int ph = 0; ph < 2; ++ph){
        const _Float16* A = ph ? A1 : A0;
        const h8* B = ph ? B1 : B0;
        #pragma unroll
        for (int kt = 0; kt < 4; ++kt){
            h8 a[4];
            #pragma unroll
            for (int s = 0; s < 4; ++s){
                int row = m0 + s*16 + rl;
                row = min(row, M-1);
                a[s] = *(const h8*)(A + (size_t)row*128 + kt*32 + kg*8);
            }
            #pragma unroll
            for (int j = 0; j < 8; ++j){
                h8 b = B[(kt*8 + j)*64 + lane];
                #pragma unroll
                for (int s = 0; s < 4; ++s)
                    acc[s][j] = __builtin_amdgcn_mfma_f32_16x16x32_f16(a[s], b, acc[s][j], 0, 0, 0);
            }
        }
    }
    #pragma unroll
    for (int j = 0; j < 8; ++j){
        int col = j*16 + rl;
        float bb = bias[col];
        #pragma unroll
        for (int s = 0; s < 4; ++s){
            #pragma unroll
            for (int r = 0; r < 4; ++r){
                int row = m0 + s*16 + kg*4 + r;
                float v = acc[s][j][r] + bb;
                v = v > 0.f ? v : 0.f;
                if (row < M) H[(size_t)row*128 + col] = (_Float16)v;
            }
        }
    }
}

// ---------------- GEMM 2a: P = H @ Wl2, [M x 64] ----------------
__global__ __launch_bounds__(256) void k_gemm2a(
    const _Float16* __restrict__ Hh, const h8* __restrict__ Bp,
    _Float16* __restrict__ P, int M)
{
    int wid = threadIdx.x >> 6, lane = threadIdx.x & 63;
    int m0 = (blockIdx.x*4 + wid) * 64;
    if (m0 >= M) return;
    int rl = lane & 15, kg = lane >> 4;
    f4 acc[4][4];
    #pragma unroll
    for (int s = 0; s < 4; ++s)
        #pragma unroll
        for (int j = 0; j < 4; ++j) acc[s][j] = (f4)0.0f;

    #pragma unroll
    for (int kt = 0; kt < 4; ++kt){
        h8 a[4];
        #pragma unroll
        for (int s = 0; s < 4; ++s){
            int row = m0 + s*16 + rl;
            row = min(row, M-1);
            a[s] = *(const h8*)(Hh + (size_t)row*128 + kt*32 + kg*8);
        }
        #pragma unroll
        for (int j = 0; j < 4; ++j){
            h8 b = Bp[(kt*4 + j)*64 + lane];
            #pragma unroll
            for (int s = 0; s < 4; ++s)
                acc[s][j] = __builtin_amdgcn_mfma_f32_16x16x32_f16(a[s], b, acc[s][j], 0, 0, 0);
        }
    }
    #pragma unroll
    for (int j = 0; j < 4; ++j){
        int col = j*16 + rl;
        #pragma unroll
        for (int s = 0; s < 4; ++s){
            #pragma unroll
            for (int r = 0; r < 4; ++r){
                int row = m0 + s*16 + kg*4 + r;
                if (row < M) P[(size_t)row*64 + col] = (_Float16)acc[s][j][r];
            }
        }
    }
}

// ---------------- GEMM 2b: OUT = H @ Wr2 + b2 + MP, [M x 64] f32 out ----------------
__global__ __launch_bounds__(256) void k_gemm2b(
    const _Float16* __restrict__ Hh, const h8* __restrict__ Bp,
    const float* __restrict__ bias, const _Float16* __restrict__ MP,
    float* __restrict__ OUT, int M)
{
    int wid = threadIdx.x >> 6, lane = threadIdx.x & 63;
    int m0 = (blockIdx.x*4 + wid) * 64;
    if (m0 >= M) return;
    int rl = lane & 15, kg = lane >> 4;
    f4 acc[4][4];
    #pragma unroll
    for (int s = 0; s < 4; ++s)
        #pragma unroll
        for (int j = 0; j < 4; ++j) acc[s][j] = (f4)0.0f;

    #pragma unroll
    for (int kt = 0; kt < 4; ++kt){
        h8 a[4];
        #pragma unroll
        for (int s = 0; s < 4; ++s){
            int row = m0 + s*16 + rl;
            row = min(row, M-1);
            a[s] = *(const h8*)(Hh + (size_t)row*128 + kt*32 + kg*8);
        }
        #pragma unroll
        for (int j = 0; j < 4; ++j){
            h8 b = Bp[(kt*4 + j)*64 + lane];
            #pragma unroll
            for (int s = 0; s < 4; ++s)
                acc[s][j] = __builtin_amdgcn_mfma_f32_16x16x32_f16(a[s], b, acc[s][j], 0, 0, 0);
        }
    }
    #pragma unroll
    for (int j = 0; j < 4; ++j){
        int col = j*16 + rl;
        float bb = bias[col];
        #pragma unroll
        for (int s = 0; s < 4; ++s){
            #pragma unroll
            for (int r = 0; r < 4; ++r){
                int row = m0 + s*16 + kg*4 + r;
                if (row < M){
                    float v = acc[s][j][r] + bb + (float)MP[(size_t)row*64 + col];
                    OUT[(size_t)row*64 + col] = v;
                }
            }
        }
    }
}

extern "C" void kernel_launch(void* const* d_in, const int* in_sizes, int n_in,
                              void* d_out, int out_size, void* d_ws, size_t ws_size,
                              hipStream_t stream) {
    const float* x   = (const float*)d_in[0];
    const int*   ei  = (const int*)d_in[1];
    const float* Wl1 = (const float*)d_in[2];
    const float* bl1 = (const float*)d_in[3];
    const float* Wr1 = (const float*)d_in[4];
    const float* Wl2 = (const float*)d_in[5];
    const float* bl2 = (const float*)d_in[6];
    const float* Wr2 = (const float*)d_in[7];

    const int N = in_sizes[0] / IN_C;
    const int E = in_sizes[1] / 2;
    const int* src = ei;
    const int* dst = ei + E;

    const int NBLK = (E + EPB - 1) / EPB;
    const int n_s  = NBUCK * NBLK;

    // workspace carve (256B aligned)
    char* w = (char*)d_ws;
    size_t off = 0;
    auto alloc = [&](size_t bytes) -> char* {
        char* p = w + off;
        off = (off + bytes + 255) & ~(size_t)255;
        return p;
    };
    int* histT      = (int*)alloc((size_t)n_s*4);
    int* tmp        = (int*)alloc((size_t)n_s*4);
    int* S          = (int*)alloc((size_t)n_s*4);
    int* bsum       = (int*)alloc(4096);
    unsigned* sorted= (unsigned*)alloc((size_t)E*4);
    int* csr        = (int*)alloc((size_t)E*4);
    int* row_start  = (int*)alloc((size_t)(N+1)*4);
    _Float16* xh    = (_Float16*)alloc((size_t)N*IN_C*2);
    _Float16* m1h   = (_Float16*)alloc((size_t)N*IN_C*2);
    _Float16* hh    = (_Float16*)alloc((size_t)N*HID_C*2);
    _Float16* ph    = (_Float16*)alloc((size_t)N*OUT_C*2);
    _Float16* mph   = (_Float16*)alloc((size_t)N*OUT_C*2);
    _Float16* wl1p  = (_Float16*)alloc(4*8*64*8*2);
    _Float16* wr1p  = (_Float16*)alloc(4*8*64*8*2);
    _Float16* wl2p  = (_Float16*)alloc(4*4*64*8*2);
    _Float16* wr2p  = (_Float16*)alloc(4*4*64*8*2);

    const int SB = (n_s + 255) / 256;

    k_hist   <<<NBLK, 256, 0, stream>>>(dst, E, histT, NBLK);
    k_scanA  <<<SB, 256, 0, stream>>>(histT, tmp, bsum, n_s);
    k_scanB  <<<1, 1024, 0, stream>>>(bsum, SB);
    k_scanCg <<<SB, 256, 0, stream>>>(tmp, bsum, S, n_s);
    k_scatter<<<NBLK, 256, 0, stream>>>(src, dst, E, S, NBLK, sorted);
    k_csr    <<<NBUCK, 512, 0, stream>>>(sorted, S, NBLK, E, N, csr, row_start);

    const int n8 = N*IN_C/8;
    k_cvt<<<(n8 + 255)/256, 256, 0, stream>>>(x, (h8*)xh, n8);
    k_pack<<<24, 256, 0, stream>>>(Wl1, Wr1, Wl2, Wr2, wl1p, wr1p, wl2p, wr2p);

    k_agg1<<<(N + 3)/4, 256, 0, stream>>>(row_start, csr, (const unsigned*)xh, (unsigned*)m1h, N);

    const int GB = (N + 255)/256;   // 64 rows per wave, 4 waves per block
    k_gemm1<<<GB, 256, 0, stream>>>(m1h, xh, (const h8*)wl1p, (const h8*)wr1p, bl1, hh, N);
    k_gemm2a<<<GB, 256, 0, stream>>>(hh, (const h8*)wl2p, ph, N);
    k_agg2<<<(N + 3)/4, 256, 0, stream>>>(row_start, csr, (const unsigned*)ph, (unsigned*)mph, N);
    k_gemm2b<<<GB, 256, 0, stream>>>(hh, (const h8*)wr2p, bl2, mph, (float*)d_out, N);
}

// Round 3
// 241.537 us; speedup vs baseline: 1.8613x; 1.2084x over previous
//
#include <hip/hip_runtime.h>
#include <hip/hip_bf16.h>
#include <stdint.h>

#define IN_C 128
#define HID_C 128
#define OUT_C 64

#define NBUCK 256
#define BSH 9
#define EPB 4096

typedef _Float16 h8 __attribute__((ext_vector_type(8)));
typedef _Float16 h2 __attribute__((ext_vector_type(2)));
typedef float f4 __attribute__((ext_vector_type(4)));
typedef unsigned u4 __attribute__((ext_vector_type(4)));

__device__ inline float h2lo(unsigned v){ h2 t = __builtin_bit_cast(h2, v); return (float)t[0]; }
__device__ inline float h2hi(unsigned v){ h2 t = __builtin_bit_cast(h2, v); return (float)t[1]; }
__device__ inline unsigned packh2(float a, float b){ h2 t; t[0]=(_Float16)a; t[1]=(_Float16)b; return __builtin_bit_cast(unsigned, t); }

// ---------------- CSR build: atomic-free counting sort ----------------
__global__ __launch_bounds__(256) void k_hist(const int* __restrict__ dst, int E,
                                              int* __restrict__ histT, int NBLK){
    __shared__ int h[NBUCK];
    int t = threadIdx.x;
    h[t] = 0; __syncthreads();
    int e0 = blockIdx.x*EPB, e1 = min(E, e0 + EPB);
    for (int e = e0 + t; e < e1; e += 256) atomicAdd(&h[((unsigned)dst[e]) >> BSH], 1);
    __syncthreads();
    histT[t*NBLK + blockIdx.x] = h[t];
}

__global__ void k_scanA(const int* __restrict__ cnt, int* __restrict__ tmp, int* __restrict__ bsum, int n){
    __shared__ int s[256];
    int t = threadIdx.x, g = blockIdx.x*256 + t;
    int v = (g < n) ? cnt[g] : 0;
    s[t] = v; __syncthreads();
    for (int off = 1; off < 256; off <<= 1){
        int a = (t >= off) ? s[t-off] : 0;
        __syncthreads();
        s[t] += a;
        __syncthreads();
    }
    int excl = (t == 0) ? 0 : s[t-1];
    if (g < n) tmp[g] = excl;
    if (t == 255) bsum[blockIdx.x] = s[255];
}

__global__ void k_scanB(int* __restrict__ bsum, int nb){
    __shared__ int s[1024];
    int t = threadIdx.x;
    int v = (t < nb) ? bsum[t] : 0;
    s[t] = v; __syncthreads();
    for (int off = 1; off < 1024; off <<= 1){
        int a = (t >= off) ? s[t-off] : 0;
        __syncthreads();
        s[t] += a;
        __syncthreads();
    }
    int excl = (t == 0) ? 0 : s[t-1];
    if (t < nb) bsum[t] = excl;
}

__global__ void k_scanCg(const int* __restrict__ tmp, const int* __restrict__ bsum,
                         int* __restrict__ S, int n){
    int g = blockIdx.x*256 + threadIdx.x;
    if (g < n) S[g] = tmp[g] + bsum[blockIdx.x];
}

__global__ __launch_bounds__(256) void k_scatter(const int* __restrict__ src, const int* __restrict__ dst,
                                                 int E, const int* __restrict__ S, int NBLK,
                                                 unsigned* __restrict__ sorted){
    __shared__ int off[NBUCK];
    int t = threadIdx.x;
    off[t] = S[t*NBLK + blockIdx.x];
    __syncthreads();
    int e0 = blockIdx.x*EPB, e1 = min(E, e0 + EPB);
    for (int e = e0 + t; e < e1; e += 256){
        int d = dst[e];
        int b = ((unsigned)d) >> BSH;
        int p = atomicAdd(&off[b], 1);
        sorted[p] = (unsigned)src[e] | (((unsigned)(d & ((1<<BSH)-1))) << 17);
    }
}

__global__ __launch_bounds__(512) void k_csr(const unsigned* __restrict__ sorted, const int* __restrict__ S,
                                             int NBLK, int E, int N,
                                             int* __restrict__ csr, int* __restrict__ row_start){
    __shared__ int cnt[512];
    __shared__ int sc[512];
    int b = blockIdx.x, t = threadIdx.x;
    int bs = S[b*NBLK];
    int be = (b == NBUCK-1) ? E : S[(b+1)*NBLK];
    cnt[t] = 0; __syncthreads();
    for (int e = bs + t; e < be; e += 512) atomicAdd(&cnt[sorted[e] >> 17], 1);
    __syncthreads();
    sc[t] = cnt[t]; __syncthreads();
    for (int off = 1; off < 512; off <<= 1){
        int a = (t >= off) ? sc[t-off] : 0;
        __syncthreads();
        sc[t] += a;
        __syncthreads();
    }
    int excl = sc[t] - cnt[t];
    int nid = (b << BSH) + t;
    if (nid < N) row_start[nid] = bs + excl;
    if (t == 0 && b == (N >> BSH)) row_start[N] = E;
    __syncthreads();
    cnt[t] = excl;
    __syncthreads();
    for (int e = bs + t; e < be; e += 512){
        unsigned v = sorted[e];
        int dl = v >> 17;
        int p = atomicAdd(&cnt[dl], 1);
        csr[bs + p] = (int)(v & 0x1FFFFu);
    }
}

// ---------------- fp32 -> fp16 conversion ----------------
__global__ void k_cvt(const float* __restrict__ x, h8* __restrict__ xh, int n8){
    int g = blockIdx.x*256 + threadIdx.x;
    if (g < n8){
        const f4* xp = (const f4*)(x + (size_t)g*8);
        f4 a = xp[0], b = xp[1];
        h8 o;
        o[0]=(_Float16)a[0]; o[1]=(_Float16)a[1]; o[2]=(_Float16)a[2]; o[3]=(_Float16)a[3];
        o[4]=(_Float16)b[0]; o[5]=(_Float16)b[1]; o[6]=(_Float16)b[2]; o[7]=(_Float16)b[3];
        xh[g] = o;
    }
}

// ---------------- weight packing: frag(kt,jt): lane holds W[kt*32+(l>>4)*8+r][jt*16+(l&15)]
// (B-frag of W == A-frag of W^T; used as A-operand in the transposed GEMM)
__device__ inline void pack_one(const float* __restrict__ W, int C, _Float16* __restrict__ outp, int tid){
    int l = tid & 63;
    int f = tid >> 6;
    int NJT = C / 16;
    int kt = f / NJT;
    int jt = f - kt*NJT;
    int kbase = kt*32 + (l >> 4)*8;
    int col   = jt*16 + (l & 15);
    h8 o;
    #pragma unroll
    for (int r = 0; r < 8; ++r) o[r] = (_Float16)W[(kbase + r)*C + col];
    ((h8*)outp)[f*64 + l] = o;
}

__global__ void k_pack(const float* __restrict__ Wl1, const float* __restrict__ Wr1,
                       const float* __restrict__ Wl2, const float* __restrict__ Wr2,
                       _Float16* __restrict__ wl1p, _Float16* __restrict__ wr1p,
                       _Float16* __restrict__ wl2p, _Float16* __restrict__ wr2p){
    int tid = blockIdx.x*256 + threadIdx.x;
    if (tid < 2048)        pack_one(Wl1, 128, wl1p, tid);
    else if (tid < 4096)   pack_one(Wr1, 128, wr1p, tid - 2048);
    else if (tid < 5120)   pack_one(Wl2,  64, wl2p, tid - 4096);
    else if (tid < 6144)   pack_one(Wr2,  64, wr2p, tid - 5120);
}

// ---------------- aggregation 1: mean of xh (128 f16 = 64 u32) per node ----------------
__global__ void k_agg1(const int* __restrict__ row_start, const int* __restrict__ csr,
                       const unsigned* __restrict__ xh32, unsigned* __restrict__ mh32, int n){
    int wave = (int)((blockIdx.x*(unsigned)blockDim.x + threadIdx.x) >> 6);
    int lane = threadIdx.x & 63;
    if (wave >= n) return;
    int base = row_start[wave], end = row_start[wave+1];
    int deg = end - base;
    float a0=0,a1=0,b0=0,b1=0,c0=0,c1=0,d0=0,d1=0;
    int i = base;
    for (; i + 4 <= end; i += 4){
        int e0 = csr[i], e1 = csr[i+1], e2 = csr[i+2], e3 = csr[i+3];
        unsigned v0 = xh32[(size_t)e0*64 + lane];
        unsigned v1 = xh32[(size_t)e1*64 + lane];
        unsigned v2 = xh32[(size_t)e2*64 + lane];
        unsigned v3 = xh32[(size_t)e3*64 + lane];
        a0 += h2lo(v0); a1 += h2hi(v0);
        b0 += h2lo(v1); b1 += h2hi(v1);
        c0 += h2lo(v2); c1 += h2hi(v2);
        d0 += h2lo(v3); d1 += h2hi(v3);
    }
    for (; i < end; ++i){
        int e = csr[i];
        unsigned v = xh32[(size_t)e*64 + lane];
        a0 += h2lo(v); a1 += h2hi(v);
    }
    float s0 = (a0 + b0) + (c0 + d0);
    float s1 = (a1 + b1) + (c1 + d1);
    float sc = 1.0f / (float)max(deg, 1);
    mh32[(size_t)wave*64 + lane] = packh2(s0*sc, s1*sc);
}

// ---------------- fused GEMM: H^T in-register, then P = H@Wl2 (f16) and Q = H@Wr2+b2 (f32 -> d_out)
// Transposed-operand trick: mfma(W_frag, node_frag) gives C with col(lane&15)=node,
// row((lane>>4)*4+r)=out-feature. Layer-2 B-frag built from H^T C-layout by pure
// cross-lane shuffles at fixed (lane&15).
__global__ __launch_bounds__(256, 4) void k_gemm_fused(
    const _Float16* __restrict__ A0,   // m1h [M][128] f16
    const _Float16* __restrict__ A1,   // xh  [M][128] f16
    const h8* __restrict__ B0,         // wl1p frags
    const h8* __restrict__ B1,         // wr1p frags
    const float* __restrict__ bias1,
    const h8* __restrict__ W2l,        // wl2p frags
    const h8* __restrict__ W2r,        // wr2p frags
    const float* __restrict__ bias2,
    _Float16* __restrict__ P,          // [M][64] f16
    float* __restrict__ Q,             // [M][64] f32 (aliases d_out)
    int M)
{
    int wid = threadIdx.x >> 6, lane = threadIdx.x & 63;
    int m0 = (blockIdx.x*4 + wid) * 16;
    if (m0 >= M) return;
    int m = lane & 15, kg = lane >> 4;
    int rowc = min(m0 + m, M-1);

    // ---- layer 1: H^T tile (128 feats x 16 nodes) ----
    f4 acc[8];
    #pragma unroll
    for (int j = 0; j < 8; ++j) acc[j] = (f4)0.0f;

    #pragma unroll
    for (int ph = 0; ph < 2; ++ph){
        const _Float16* A = ph ? A1 : A0;
        const h8* B = ph ? B1 : B0;
        #pragma unroll
        for (int kt = 0; kt < 4; ++kt){
            h8 nf = *(const h8*)(A + (size_t)rowc*128 + kt*32 + kg*8);  // B-operand: node features
            #pragma unroll
            for (int j = 0; j < 8; ++j){
                h8 wf = B[(kt*8 + j)*64 + lane];                        // A-operand: W^T frag
                acc[j] = __builtin_amdgcn_mfma_f32_16x16x32_f16(wf, nf, acc[j], 0, 0, 0);
            }
        }
    }

    // ---- epilogue 1: bias + relu + pack to f16 pairs ----
    // hreg[2j+p] holds feats {j*16+kg*4+2p, +1} of node m (as 2xf16 in u32)
    unsigned hreg[16];
    #pragma unroll
    for (int j = 0; j < 8; ++j){
        f4 bb = *(const f4*)(bias1 + j*16 + kg*4);
        float v0 = acc[j][0] + bb[0]; v0 = v0 > 0.f ? v0 : 0.f;
        float v1 = acc[j][1] + bb[1]; v1 = v1 > 0.f ? v1 : 0.f;
        float v2 = acc[j][2] + bb[2]; v2 = v2 > 0.f ? v2 : 0.f;
        float v3 = acc[j][3] + bb[3]; v3 = v3 > 0.f ? v3 : 0.f;
        hreg[2*j]   = packh2(v0, v1);
        hreg[2*j+1] = packh2(v2, v3);
    }

    // ---- layer 2: P^T and Q^T from shuffled H frags ----
    f4 accP[4], accQ[4];
    #pragma unroll
    for (int j = 0; j < 4; ++j){ accP[j] = (f4)0.0f; accQ[j] = (f4)0.0f; }

    int srcA = ((kg & 1) * 2) * 16 + m;   // source lane for feats kt*32+8kg+0..3
    int srcB = srcA + 16;                 // source lane for feats kt*32+8kg+4..7
    bool hi = (kg >> 1) & 1;

    #pragma unroll
    for (int kt = 0; kt < 4; ++kt){
        unsigned sA0 = (unsigned)__shfl((int)hreg[4*kt+0], srcA, 64);
        unsigned sA1 = (unsigned)__shfl((int)hreg[4*kt+1], srcA, 64);
        unsigned sA2 = (unsigned)__shfl((int)hreg[4*kt+2], srcA, 64);
        unsigned sA3 = (unsigned)__shfl((int)hreg[4*kt+3], srcA, 64);
        unsigned sB0 = (unsigned)__shfl((int)hreg[4*kt+0], srcB, 64);
        unsigned sB1 = (unsigned)__shfl((int)hreg[4*kt+1], srcB, 64);
        unsigned sB2 = (unsigned)__shfl((int)hreg[4*kt+2], srcB, 64);
        unsigned sB3 = (unsigned)__shfl((int)hreg[4*kt+3], srcB, 64);
        u4 u;
        u[0] = hi ? sA2 : sA0;
        u[1] = hi ? sA3 : sA1;
        u[2] = hi ? sB2 : sB0;
        u[3] = hi ? sB3 : sB1;
        h8 hf = __builtin_bit_cast(h8, u);   // B-frag: H[m][kt*32+kg*8 .. +8]
        #pragma unroll
        for (int j2 = 0; j2 < 4; ++j2){
            accP[j2] = __builtin_amdgcn_mfma_f32_16x16x32_f16(W2l[(kt*4 + j2)*64 + lane], hf, accP[j2], 0, 0, 0);
            accQ[j2] = __builtin_amdgcn_mfma_f32_16x16x32_f16(W2r[(kt*4 + j2)*64 + lane], hf, accQ[j2], 0, 0, 0);
        }
    }

    // ---- write P (f16) and Q (f32) ----
    int node = m0 + m;
    if (node < M){
        #pragma unroll
        for (int j2 = 0; j2 < 4; ++j2){
            int f = j2*16 + kg*4;
            unsigned p0 = packh2(accP[j2][0], accP[j2][1]);
            unsigned p1 = packh2(accP[j2][2], accP[j2][3]);
            uint2 pv; pv.x = p0; pv.y = p1;
            *(uint2*)((unsigned short*)P + (size_t)node*64 + f) = pv;
            f4 bb2 = *(const f4*)(bias2 + f);
            f4 qv;
            qv[0] = accQ[j2][0] + bb2[0];
            qv[1] = accQ[j2][1] + bb2[1];
            qv[2] = accQ[j2][2] + bb2[2];
            qv[3] = accQ[j2][3] + bb2[3];
            *(f4*)(Q + (size_t)node*64 + f) = qv;
        }
    }
}

// ---------------- aggregation 2 fused: out = Q + mean-gather(P) ----------------
__global__ void k_agg2f(const int* __restrict__ row_start, const int* __restrict__ csr,
                        const unsigned* __restrict__ ph32, const float* __restrict__ Q,
                        float* __restrict__ out, int n){
    int wave = (int)((blockIdx.x*(unsigned)blockDim.x + threadIdx.x) >> 6);
    int lane = threadIdx.x & 63;
    if (wave >= n) return;
    int c = lane & 31, h = lane >> 5;
    int base = row_start[wave], end = row_start[wave+1];
    int deg = end - base;
    float a0=0,a1=0,b0=0,b1=0;
    int i = base + h;
    for (; i + 2 < end; i += 4){
        int e0 = csr[i], e1 = csr[i+2];
        unsigned v0 = ph32[(size_t)e0*32 + c];
        unsigned v1 = ph32[(size_t)e1*32 + c];
        a0 += h2lo(v0); a1 += h2hi(v0);
        b0 += h2lo(v1); b1 += h2hi(v1);
    }
    for (; i < end; i += 2){
        int e = csr[i];
        unsigned v = ph32[(size_t)e*32 + c];
        a0 += h2lo(v); a1 += h2hi(v);
    }
    a0 += b0; a1 += b1;
    a0 += __shfl_xor(a0, 32);
    a1 += __shfl_xor(a1, 32);
    if (h == 0){
        float sc = 1.0f / (float)max(deg, 1);
        const float2 q = *(const float2*)(Q + (size_t)wave*64 + 2*c);
        float2 o;
        o.x = a0*sc + q.x;
        o.y = a1*sc + q.y;
        *(float2*)(out + (size_t)wave*64 + 2*c) = o;
    }
}

extern "C" void kernel_launch(void* const* d_in, const int* in_sizes, int n_in,
                              void* d_out, int out_size, void* d_ws, size_t ws_size,
                              hipStream_t stream) {
    const float* x   = (const float*)d_in[0];
    const int*   ei  = (const int*)d_in[1];
    const float* Wl1 = (const float*)d_in[2];
    const float* bl1 = (const float*)d_in[3];
    const float* Wr1 = (const float*)d_in[4];
    const float* Wl2 = (const float*)d_in[5];
    const float* bl2 = (const float*)d_in[6];
    const float* Wr2 = (const float*)d_in[7];

    const int N = in_sizes[0] / IN_C;
    const int E = in_sizes[1] / 2;
    const int* src = ei;
    const int* dst = ei + E;

    const int NBLK = (E + EPB - 1) / EPB;
    const int n_s  = NBUCK * NBLK;

    char* w = (char*)d_ws;
    size_t off = 0;
    auto alloc = [&](size_t bytes) -> char* {
        char* p = w + off;
        off = (off + bytes + 255) & ~(size_t)255;
        return p;
    };
    int* histT      = (int*)alloc((size_t)n_s*4);
    int* tmp        = (int*)alloc((size_t)n_s*4);
    int* S          = (int*)alloc((size_t)n_s*4);
    int* bsum       = (int*)alloc(4096);
    unsigned* sorted= (unsigned*)alloc((size_t)E*4);
    int* csr        = (int*)alloc((size_t)E*4);
    int* row_start  = (int*)alloc((size_t)(N+1)*4);
    _Float16* xh    = (_Float16*)alloc((size_t)N*IN_C*2);
    _Float16* m1h   = (_Float16*)alloc((size_t)N*IN_C*2);
    _Float16* ph    = (_Float16*)alloc((size_t)N*OUT_C*2);
    _Float16* wl1p  = (_Float16*)alloc(4*8*64*8*2);
    _Float16* wr1p  = (_Float16*)alloc(4*8*64*8*2);
    _Float16* wl2p  = (_Float16*)alloc(4*4*64*8*2);
    _Float16* wr2p  = (_Float16*)alloc(4*4*64*8*2);

    const int SB = (n_s + 255) / 256;

    k_hist   <<<NBLK, 256, 0, stream>>>(dst, E, histT, NBLK);
    k_scanA  <<<SB, 256, 0, stream>>>(histT, tmp, bsum, n_s);
    k_scanB  <<<1, 1024, 0, stream>>>(bsum, SB);
    k_scanCg <<<SB, 256, 0, stream>>>(tmp, bsum, S, n_s);
    k_scatter<<<NBLK, 256, 0, stream>>>(src, dst, E, S, NBLK, sorted);
    k_csr    <<<NBUCK, 512, 0, stream>>>(sorted, S, NBLK, E, N, csr, row_start);

    const int n8 = N*IN_C/8;
    k_cvt<<<(n8 + 255)/256, 256, 0, stream>>>(x, (h8*)xh, n8);
    k_pack<<<24, 256, 0, stream>>>(Wl1, Wr1, Wl2, Wr2, wl1p, wr1p, wl2p, wr2p);

    k_agg1<<<(N + 3)/4, 256, 0, stream>>>(row_start, csr, (const unsigned*)xh, (unsigned*)m1h, N);

    float* Q = (float*)d_out;   // Q written straight into d_out, then agg2f adds the mean in-place
    const int GB2 = (N + 63)/64;   // 16 rows per wave, 4 waves per block
    k_gemm_fused<<<GB2, 256, 0, stream>>>(m1h, xh, (const h8*)wl1p, (const h8*)wr1p, bl1,
                                          (const h8*)wl2p, (const h8*)wr2p, bl2,
                                          ph, Q, N);

    k_agg2f<<<(N + 3)/4, 256, 0, stream>>>(row_start, csr, (const unsigned*)ph, Q, (float*)d_out, N);
}

// Round 4
// 235.211 us; speedup vs baseline: 1.9113x; 1.0269x over previous
//
#include <hip/hip_runtime.h>
#include <hip/hip_bf16.h>
#include <stdint.h>

#define IN_C 128
#define HID_C 128
#define OUT_C 64

#define NBUCK 256
#define BSH 9
#define EPB 4096

typedef _Float16 h8 __attribute__((ext_vector_type(8)));
typedef _Float16 h2 __attribute__((ext_vector_type(2)));
typedef float f4 __attribute__((ext_vector_type(4)));
typedef float f2 __attribute__((ext_vector_type(2)));
typedef unsigned u4 __attribute__((ext_vector_type(4)));

__device__ inline float h2lo(unsigned v){ h2 t = __builtin_bit_cast(h2, v); return (float)t[0]; }
__device__ inline float h2hi(unsigned v){ h2 t = __builtin_bit_cast(h2, v); return (float)t[1]; }
__device__ inline unsigned packh2(float a, float b){ h2 t; t[0]=(_Float16)a; t[1]=(_Float16)b; return __builtin_bit_cast(unsigned, t); }

// ---------------- CSR build: atomic-free counting sort ----------------
__global__ __launch_bounds__(256) void k_hist(const int* __restrict__ dst, int E,
                                              int* __restrict__ histT, int NBLK){
    __shared__ int h[NBUCK];
    int t = threadIdx.x;
    h[t] = 0; __syncthreads();
    int e0 = blockIdx.x*EPB, e1 = min(E, e0 + EPB);
    for (int e = e0 + t; e < e1; e += 256) atomicAdd(&h[((unsigned)dst[e]) >> BSH], 1);
    __syncthreads();
    histT[t*NBLK + blockIdx.x] = h[t];
}

__global__ void k_scanA(const int* __restrict__ cnt, int* __restrict__ tmp, int* __restrict__ bsum, int n){
    __shared__ int s[256];
    int t = threadIdx.x, g = blockIdx.x*256 + t;
    int v = (g < n) ? cnt[g] : 0;
    s[t] = v; __syncthreads();
    for (int off = 1; off < 256; off <<= 1){
        int a = (t >= off) ? s[t-off] : 0;
        __syncthreads();
        s[t] += a;
        __syncthreads();
    }
    int excl = (t == 0) ? 0 : s[t-1];
    if (g < n) tmp[g] = excl;
    if (t == 255) bsum[blockIdx.x] = s[255];
}

__global__ void k_scanB(int* __restrict__ bsum, int nb){
    __shared__ int s[1024];
    int t = threadIdx.x;
    int v = (t < nb) ? bsum[t] : 0;
    s[t] = v; __syncthreads();
    for (int off = 1; off < 1024; off <<= 1){
        int a = (t >= off) ? s[t-off] : 0;
        __syncthreads();
        s[t] += a;
        __syncthreads();
    }
    int excl = (t == 0) ? 0 : s[t-1];
    if (t < nb) bsum[t] = excl;
}

__global__ void k_scanCg(const int* __restrict__ tmp, const int* __restrict__ bsum,
                         int* __restrict__ S, int n){
    int g = blockIdx.x*256 + threadIdx.x;
    if (g < n) S[g] = tmp[g] + bsum[blockIdx.x];
}

__global__ __launch_bounds__(256) void k_scatter(const int* __restrict__ src, const int* __restrict__ dst,
                                                 int E, const int* __restrict__ S, int NBLK,
                                                 unsigned* __restrict__ sorted){
    __shared__ int off[NBUCK];
    int t = threadIdx.x;
    off[t] = S[t*NBLK + blockIdx.x];
    __syncthreads();
    int e0 = blockIdx.x*EPB, e1 = min(E, e0 + EPB);
    for (int e = e0 + t; e < e1; e += 256){
        int d = dst[e];
        int b = ((unsigned)d) >> BSH;
        int p = atomicAdd(&off[b], 1);
        sorted[p] = (unsigned)src[e] | (((unsigned)(d & ((1<<BSH)-1))) << 17);
    }
}

__global__ __launch_bounds__(512) void k_csr(const unsigned* __restrict__ sorted, const int* __restrict__ S,
                                             int NBLK, int E, int N,
                                             int* __restrict__ csr, int* __restrict__ row_start){
    __shared__ int cnt[512];
    __shared__ int sc[512];
    int b = blockIdx.x, t = threadIdx.x;
    int bs = S[b*NBLK];
    int be = (b == NBUCK-1) ? E : S[(b+1)*NBLK];
    cnt[t] = 0; __syncthreads();
    for (int e = bs + t; e < be; e += 512) atomicAdd(&cnt[sorted[e] >> 17], 1);
    __syncthreads();
    sc[t] = cnt[t]; __syncthreads();
    for (int off = 1; off < 512; off <<= 1){
        int a = (t >= off) ? sc[t-off] : 0;
        __syncthreads();
        sc[t] += a;
        __syncthreads();
    }
    int excl = sc[t] - cnt[t];
    int nid = (b << BSH) + t;
    if (nid < N) row_start[nid] = bs + excl;
    if (t == 0 && b == (N >> BSH)) row_start[N] = E;
    __syncthreads();
    cnt[t] = excl;
    __syncthreads();
    for (int e = bs + t; e < be; e += 512){
        unsigned v = sorted[e];
        int dl = v >> 17;
        int p = atomicAdd(&cnt[dl], 1);
        csr[bs + p] = (int)(v & 0x1FFFFu);
    }
}

// ---------------- fp32 -> fp16 + fp8 conversion ----------------
__global__ void k_cvt(const float* __restrict__ x, h8* __restrict__ xh, uint2* __restrict__ x8, int n8){
    int g = blockIdx.x*256 + threadIdx.x;
    if (g < n8){
        const f4* xp = (const f4*)(x + (size_t)g*8);
        f4 a = xp[0], b = xp[1];
        h8 o;
        o[0]=(_Float16)a[0]; o[1]=(_Float16)a[1]; o[2]=(_Float16)a[2]; o[3]=(_Float16)a[3];
        o[4]=(_Float16)b[0]; o[5]=(_Float16)b[1]; o[6]=(_Float16)b[2]; o[7]=(_Float16)b[3];
        xh[g] = o;
        int w0 = __builtin_amdgcn_cvt_pk_fp8_f32(a[0], a[1], 0, false);
        w0     = __builtin_amdgcn_cvt_pk_fp8_f32(a[2], a[3], w0, true);
        int w1 = __builtin_amdgcn_cvt_pk_fp8_f32(b[0], b[1], 0, false);
        w1     = __builtin_amdgcn_cvt_pk_fp8_f32(b[2], b[3], w1, true);
        uint2 p; p.x = (unsigned)w0; p.y = (unsigned)w1;
        x8[g] = p;
    }
}

// ---------------- weight packing: frag(kt,jt): lane holds W[kt*32+(l>>4)*8+r][jt*16+(l&15)]
__device__ inline void pack_one(const float* __restrict__ W, int C, _Float16* __restrict__ outp, int tid){
    int l = tid & 63;
    int f = tid >> 6;
    int NJT = C / 16;
    int kt = f / NJT;
    int jt = f - kt*NJT;
    int kbase = kt*32 + (l >> 4)*8;
    int col   = jt*16 + (l & 15);
    h8 o;
    #pragma unroll
    for (int r = 0; r < 8; ++r) o[r] = (_Float16)W[(kbase + r)*C + col];
    ((h8*)outp)[f*64 + l] = o;
}

__global__ void k_pack(const float* __restrict__ Wl1, const float* __restrict__ Wr1,
                       const float* __restrict__ Wl2, const float* __restrict__ Wr2,
                       _Float16* __restrict__ wl1p, _Float16* __restrict__ wr1p,
                       _Float16* __restrict__ wl2p, _Float16* __restrict__ wr2p){
    int tid = blockIdx.x*256 + threadIdx.x;
    if (tid < 2048)        pack_one(Wl1, 128, wl1p, tid);
    else if (tid < 4096)   pack_one(Wr1, 128, wr1p, tid - 2048);
    else if (tid < 5120)   pack_one(Wl2,  64, wl2p, tid - 4096);
    else if (tid < 6144)   pack_one(Wr2,  64, wr2p, tid - 5120);
}

// ---------------- aggregation 1: mean of x8 (128 fp8 = 32 u32) per node, fp16 out ----------------
// lanes 0-31: even csr slots, lanes 32-63: odd csr slots; lane c owns features 4c..4c+3
__global__ void k_agg1(const int* __restrict__ row_start, const int* __restrict__ csr,
                       const unsigned* __restrict__ x8, unsigned* __restrict__ mh32, int n){
    int wave = (int)((blockIdx.x*(unsigned)blockDim.x + threadIdx.x) >> 6);
    int lane = threadIdx.x & 63;
    if (wave >= n) return;
    int c = lane & 31, h = lane >> 5;
    int base = row_start[wave], end = row_start[wave+1];
    int deg = end - base;
    f2 a0 = {0.f, 0.f}, a1 = {0.f, 0.f}, b0 = {0.f, 0.f}, b1 = {0.f, 0.f};
    int i = base + h;
    for (; i + 2 < end; i += 4){
        int e0 = csr[i], e1 = csr[i+2];
        unsigned v0 = x8[(size_t)e0*32 + c];
        unsigned v1 = x8[(size_t)e1*32 + c];
        a0 += __builtin_amdgcn_cvt_pk_f32_fp8(v0, false);
        a1 += __builtin_amdgcn_cvt_pk_f32_fp8(v0, true);
        b0 += __builtin_amdgcn_cvt_pk_f32_fp8(v1, false);
        b1 += __builtin_amdgcn_cvt_pk_f32_fp8(v1, true);
    }
    for (; i < end; i += 2){
        int e = csr[i];
        unsigned v = x8[(size_t)e*32 + c];
        a0 += __builtin_amdgcn_cvt_pk_f32_fp8(v, false);
        a1 += __builtin_amdgcn_cvt_pk_f32_fp8(v, true);
    }
    a0 += b0; a1 += b1;
    a0[0] += __shfl_xor(a0[0], 32);
    a0[1] += __shfl_xor(a0[1], 32);
    a1[0] += __shfl_xor(a1[0], 32);
    a1[1] += __shfl_xor(a1[1], 32);
    if (h == 0){
        float sc = 1.0f / (float)max(deg, 1);
        uint2 o;
        o.x = packh2(a0[0]*sc, a0[1]*sc);
        o.y = packh2(a1[0]*sc, a1[1]*sc);
        *(uint2*)(mh32 + (size_t)wave*64 + 2*c) = o;
    }
}

// ---------------- fused GEMM: H^T in-register, then P = H@Wl2 (f16) and Q = H@Wr2+b2 (f32 -> d_out)
__global__ __launch_bounds__(256, 4) void k_gemm_fused(
    const _Float16* __restrict__ A0,   // m1h [M][128] f16
    const _Float16* __restrict__ A1,   // xh  [M][128] f16
    const h8* __restrict__ B0,         // wl1p frags
    const h8* __restrict__ B1,         // wr1p frags
    const float* __restrict__ bias1,
    const h8* __restrict__ W2l,        // wl2p frags
    const h8* __restrict__ W2r,        // wr2p frags
    const float* __restrict__ bias2,
    _Float16* __restrict__ P,          // [M][64] f16
    float* __restrict__ Q,             // [M][64] f32 (aliases d_out)
    int M)
{
    int wid = threadIdx.x >> 6, lane = threadIdx.x & 63;
    int m0 = (blockIdx.x*4 + wid) * 16;
    if (m0 >= M) return;
    int m = lane & 15, kg = lane >> 4;
    int rowc = min(m0 + m, M-1);

    f4 acc[8];
    #pragma unroll
    for (int j = 0; j < 8; ++j) acc[j] = (f4)0.0f;

    #pragma unroll
    for (int ph = 0; ph < 2; ++ph){
        const _Float16* A = ph ? A1 : A0;
        const h8* B = ph ? B1 : B0;
        #pragma unroll
        for (int kt = 0; kt < 4; ++kt){
            h8 nf = *(const h8*)(A + (size_t)rowc*128 + kt*32 + kg*8);
            #pragma unroll
            for (int j = 0; j < 8; ++j){
                h8 wf = B[(kt*8 + j)*64 + lane];
                acc[j] = __builtin_amdgcn_mfma_f32_16x16x32_f16(wf, nf, acc[j], 0, 0, 0);
            }
        }
    }

    unsigned hreg[16];
    #pragma unroll
    for (int j = 0; j < 8; ++j){
        f4 bb = *(const f4*)(bias1 + j*16 + kg*4);
        float v0 = acc[j][0] + bb[0]; v0 = v0 > 0.f ? v0 : 0.f;
        float v1 = acc[j][1] + bb[1]; v1 = v1 > 0.f ? v1 : 0.f;
        float v2 = acc[j][2] + bb[2]; v2 = v2 > 0.f ? v2 : 0.f;
        float v3 = acc[j][3] + bb[3]; v3 = v3 > 0.f ? v3 : 0.f;
        hreg[2*j]   = packh2(v0, v1);
        hreg[2*j+1] = packh2(v2, v3);
    }

    f4 accP[4], accQ[4];
    #pragma unroll
    for (int j = 0; j < 4; ++j){ accP[j] = (f4)0.0f; accQ[j] = (f4)0.0f; }

    int srcA = ((kg & 1) * 2) * 16 + m;
    int srcB = srcA + 16;
    bool hi = (kg >> 1) & 1;

    #pragma unroll
    for (int kt = 0; kt < 4; ++kt){
        unsigned sA0 = (unsigned)__shfl((int)hreg[4*kt+0], srcA, 64);
        unsigned sA1 = (unsigned)__shfl((int)hreg[4*kt+1], srcA, 64);
        unsigned sA2 = (unsigned)__shfl((int)hreg[4*kt+2], srcA, 64);
        unsigned sA3 = (unsigned)__shfl((int)hreg[4*kt+3], srcA, 64);
        unsigned sB0 = (unsigned)__shfl((int)hreg[4*kt+0], srcB, 64);
        unsigned sB1 = (unsigned)__shfl((int)hreg[4*kt+1], srcB, 64);
        unsigned sB2 = (unsigned)__shfl((int)hreg[4*kt+2], srcB, 64);
        unsigned sB3 = (unsigned)__shfl((int)hreg[4*kt+3], srcB, 64);
        u4 u;
        u[0] = hi ? sA2 : sA0;
        u[1] = hi ? sA3 : sA1;
        u[2] = hi ? sB2 : sB0;
        u[3] = hi ? sB3 : sB1;
        h8 hf = __builtin_bit_cast(h8, u);
        #pragma unroll
        for (int j2 = 0; j2 < 4; ++j2){
            accP[j2] = __builtin_amdgcn_mfma_f32_16x16x32_f16(W2l[(kt*4 + j2)*64 + lane], hf, accP[j2], 0, 0, 0);
            accQ[j2] = __builtin_amdgcn_mfma_f32_16x16x32_f16(W2r[(kt*4 + j2)*64 + lane], hf, accQ[j2], 0, 0, 0);
        }
    }

    int node = m0 + m;
    if (node < M){
        #pragma unroll
        for (int j2 = 0; j2 < 4; ++j2){
            int f = j2*16 + kg*4;
            unsigned p0 = packh2(accP[j2][0], accP[j2][1]);
            unsigned p1 = packh2(accP[j2][2], accP[j2][3]);
            uint2 pv; pv.x = p0; pv.y = p1;
            *(uint2*)((unsigned short*)P + (size_t)node*64 + f) = pv;
            f4 bb2 = *(const f4*)(bias2 + f);
            f4 qv;
            qv[0] = accQ[j2][0] + bb2[0];
            qv[1] = accQ[j2][1] + bb2[1];
            qv[2] = accQ[j2][2] + bb2[2];
            qv[3] = accQ[j2][3] + bb2[3];
            *(f4*)(Q + (size_t)node*64 + f) = qv;
        }
    }
}

// ---------------- aggregation 2 fused: out = Q + mean-gather(P) ----------------
__global__ void k_agg2f(const int* __restrict__ row_start, const int* __restrict__ csr,
                        const unsigned* __restrict__ ph32, const float* __restrict__ Q,
                        float* __restrict__ out, int n){
    int wave = (int)((blockIdx.x*(unsigned)blockDim.x + threadIdx.x) >> 6);
    int lane = threadIdx.x & 63;
    if (wave >= n) return;
    int c = lane & 31, h = lane >> 5;
    int base = row_start[wave], end = row_start[wave+1];
    int deg = end - base;
    float a0=0,a1=0,b0=0,b1=0;
    int i = base + h;
    for (; i + 2 < end; i += 4){
        int e0 = csr[i], e1 = csr[i+2];
        unsigned v0 = ph32[(size_t)e0*32 + c];
        unsigned v1 = ph32[(size_t)e1*32 + c];
        a0 += h2lo(v0); a1 += h2hi(v0);
        b0 += h2lo(v1); b1 += h2hi(v1);
    }
    for (; i < end; i += 2){
        int e = csr[i];
        unsigned v = ph32[(size_t)e*32 + c];
        a0 += h2lo(v); a1 += h2hi(v);
    }
    a0 += b0; a1 += b1;
    a0 += __shfl_xor(a0, 32);
    a1 += __shfl_xor(a1, 32);
    if (h == 0){
        float sc = 1.0f / (float)max(deg, 1);
        const float2 q = *(const float2*)(Q + (size_t)wave*64 + 2*c);
        float2 o;
        o.x = a0*sc + q.x;
        o.y = a1*sc + q.y;
        *(float2*)(out + (size_t)wave*64 + 2*c) = o;
    }
}

extern "C" void kernel_launch(void* const* d_in, const int* in_sizes, int n_in,
                              void* d_out, int out_size, void* d_ws, size_t ws_size,
                              hipStream_t stream) {
    const float* x   = (const float*)d_in[0];
    const int*   ei  = (const int*)d_in[1];
    const float* Wl1 = (const float*)d_in[2];
    const float* bl1 = (const float*)d_in[3];
    const float* Wr1 = (const float*)d_in[4];
    const float* Wl2 = (const float*)d_in[5];
    const float* bl2 = (const float*)d_in[6];
    const float* Wr2 = (const float*)d_in[7];

    const int N = in_sizes[0] / IN_C;
    const int E = in_sizes[1] / 2;
    const int* src = ei;
    const int* dst = ei + E;

    const int NBLK = (E + EPB - 1) / EPB;
    const int n_s  = NBUCK * NBLK;

    char* w = (char*)d_ws;
    size_t off = 0;
    auto alloc = [&](size_t bytes) -> char* {
        char* p = w + off;
        off = (off + bytes + 255) & ~(size_t)255;
        return p;
    };
    int* histT      = (int*)alloc((size_t)n_s*4);
    int* tmp        = (int*)alloc((size_t)n_s*4);
    int* S          = (int*)alloc((size_t)n_s*4);
    int* bsum       = (int*)alloc(4096);
    unsigned* sorted= (unsigned*)alloc((size_t)E*4);
    int* csr        = (int*)alloc((size_t)E*4);
    int* row_start  = (int*)alloc((size_t)(N+1)*4);
    _Float16* xh    = (_Float16*)alloc((size_t)N*IN_C*2);
    unsigned* x8    = (unsigned*)alloc((size_t)N*IN_C);
    _Float16* m1h   = (_Float16*)alloc((size_t)N*IN_C*2);
    _Float16* ph    = (_Float16*)alloc((size_t)N*OUT_C*2);
    _Float16* wl1p  = (_Float16*)alloc(4*8*64*8*2);
    _Float16* wr1p  = (_Float16*)alloc(4*8*64*8*2);
    _Float16* wl2p  = (_Float16*)alloc(4*4*64*8*2);
    _Float16* wr2p  = (_Float16*)alloc(4*4*64*8*2);

    const int SB = (n_s + 255) / 256;

    k_hist   <<<NBLK, 256, 0, stream>>>(dst, E, histT, NBLK);
    k_scanA  <<<SB, 256, 0, stream>>>(histT, tmp, bsum, n_s);
    k_scanB  <<<1, 1024, 0, stream>>>(bsum, SB);
    k_scanCg <<<SB, 256, 0, stream>>>(tmp, bsum, S, n_s);
    k_scatter<<<NBLK, 256, 0, stream>>>(src, dst, E, S, NBLK, sorted);
    k_csr    <<<NBUCK, 512, 0, stream>>>(sorted, S, NBLK, E, N, csr, row_start);

    const int n8 = N*IN_C/8;
    k_cvt<<<(n8 + 255)/256, 256, 0, stream>>>(x, (h8*)xh, (uint2*)x8, n8);
    k_pack<<<24, 256, 0, stream>>>(Wl1, Wr1, Wl2, Wr2, wl1p, wr1p, wl2p, wr2p);

    k_agg1<<<(N + 3)/4, 256, 0, stream>>>(row_start, csr, x8, (unsigned*)m1h, N);

    float* Q = (float*)d_out;
    const int GB2 = (N + 63)/64;
    k_gemm_fused<<<GB2, 256, 0, stream>>>(m1h, xh, (const h8*)wl1p, (const h8*)wr1p, bl1,
                                          (const h8*)wl2p, (const h8*)wr2p, bl2,
                                          ph, Q, N);

    k_agg2f<<<(N + 3)/4, 256, 0, stream>>>(row_start, csr, (const unsigned*)ph, Q, (float*)d_out, N);
}

// Round 5
// 205.867 us; speedup vs baseline: 2.1838x; 1.1425x over previous
//
#include <hip/hip_runtime.h>
#include <hip/hip_bf16.h>
#include <stdint.h>

#define IN_C 128
#define HID_C 128
#define OUT_C 64

#define NBUCK 256
#define BSH 9
#define EPB 4096

typedef _Float16 h8 __attribute__((ext_vector_type(8)));
typedef _Float16 h2 __attribute__((ext_vector_type(2)));
typedef float f4 __attribute__((ext_vector_type(4)));
typedef float f2 __attribute__((ext_vector_type(2)));
typedef unsigned u4 __attribute__((ext_vector_type(4)));

__device__ inline float h2lo(unsigned v){ h2 t = __builtin_bit_cast(h2, v); return (float)t[0]; }
__device__ inline float h2hi(unsigned v){ h2 t = __builtin_bit_cast(h2, v); return (float)t[1]; }
__device__ inline unsigned packh2(float a, float b){ h2 t; t[0]=(_Float16)a; t[1]=(_Float16)b; return __builtin_bit_cast(unsigned, t); }

// ---------------- CSR build: atomic-free counting sort ----------------
__global__ __launch_bounds__(256) void k_hist(const int* __restrict__ dst, int E,
                                              int* __restrict__ histT, int NBLK){
    __shared__ int h[NBUCK];
    int t = threadIdx.x;
    h[t] = 0; __syncthreads();
    int e0 = blockIdx.x*EPB, e1 = min(E, e0 + EPB);
    for (int e = e0 + t; e < e1; e += 256) atomicAdd(&h[((unsigned)dst[e]) >> BSH], 1);
    __syncthreads();
    histT[t*NBLK + blockIdx.x] = h[t];
}

__global__ void k_scanA(const int* __restrict__ cnt, int* __restrict__ tmp, int* __restrict__ bsum, int n){
    __shared__ int s[256];
    int t = threadIdx.x, g = blockIdx.x*256 + t;
    int v = (g < n) ? cnt[g] : 0;
    s[t] = v; __syncthreads();
    for (int off = 1; off < 256; off <<= 1){
        int a = (t >= off) ? s[t-off] : 0;
        __syncthreads();
        s[t] += a;
        __syncthreads();
    }
    int excl = (t == 0) ? 0 : s[t-1];
    if (g < n) tmp[g] = excl;
    if (t == 255) bsum[blockIdx.x] = s[255];
}

__global__ void k_scanB(int* __restrict__ bsum, int nb){
    __shared__ int s[1024];
    int t = threadIdx.x;
    int v = (t < nb) ? bsum[t] : 0;
    s[t] = v; __syncthreads();
    for (int off = 1; off < 1024; off <<= 1){
        int a = (t >= off) ? s[t-off] : 0;
        __syncthreads();
        s[t] += a;
        __syncthreads();
    }
    int excl = (t == 0) ? 0 : s[t-1];
    if (t < nb) bsum[t] = excl;
}

// S[g] = tmp[g] + bsum[g>>8], computed on the fly by consumers (k_scanCg removed)
__global__ __launch_bounds__(256) void k_scatter(const int* __restrict__ src, const int* __restrict__ dst,
                                                 int E, const int* __restrict__ tmp, const int* __restrict__ bsum,
                                                 int NBLK, unsigned* __restrict__ sorted){
    __shared__ int off[NBUCK];
    int t = threadIdx.x;
    int g = t*NBLK + blockIdx.x;
    off[t] = tmp[g] + bsum[g >> 8];
    __syncthreads();
    int e0 = blockIdx.x*EPB, e1 = min(E, e0 + EPB);
    for (int e = e0 + t; e < e1; e += 256){
        int d = dst[e];
        int b = ((unsigned)d) >> BSH;
        int p = atomicAdd(&off[b], 1);
        sorted[p] = (unsigned)src[e] | (((unsigned)(d & ((1<<BSH)-1))) << 17);
    }
}

__global__ __launch_bounds__(512) void k_csr(const unsigned* __restrict__ sorted,
                                             const int* __restrict__ tmp, const int* __restrict__ bsum,
                                             int NBLK, int E, int N,
                                             int* __restrict__ csr, int* __restrict__ row_start){
    __shared__ int cnt[512];
    __shared__ int sc[512];
    int b = blockIdx.x, t = threadIdx.x;
    int i0 = b*NBLK;
    int bs = tmp[i0] + bsum[i0 >> 8];
    int be = (b == NBUCK-1) ? E : (tmp[i0 + NBLK] + bsum[(i0 + NBLK) >> 8]);
    cnt[t] = 0; __syncthreads();
    for (int e = bs + t; e < be; e += 512) atomicAdd(&cnt[sorted[e] >> 17], 1);
    __syncthreads();
    sc[t] = cnt[t]; __syncthreads();
    for (int off = 1; off < 512; off <<= 1){
        int a = (t >= off) ? sc[t-off] : 0;
        __syncthreads();
        sc[t] += a;
        __syncthreads();
    }
    int excl = sc[t] - cnt[t];
    int nid = (b << BSH) + t;
    if (nid < N) row_start[nid] = bs + excl;
    if (t == 0 && b == (N >> BSH)) row_start[N] = E;
    __syncthreads();
    cnt[t] = excl;
    __syncthreads();
    for (int e = bs + t; e < be; e += 512){
        unsigned v = sorted[e];
        int dl = v >> 17;
        int p = atomicAdd(&cnt[dl], 1);
        csr[bs + p] = (int)(v & 0x1FFFFu);
    }
}

// ---------------- fp32 -> fp16 + fp8 conversion ----------------
__global__ void k_cvt(const float* __restrict__ x, h8* __restrict__ xh, uint2* __restrict__ x8, int n8){
    int g = blockIdx.x*256 + threadIdx.x;
    if (g < n8){
        const f4* xp = (const f4*)(x + (size_t)g*8);
        f4 a = xp[0], b = xp[1];
        h8 o;
        o[0]=(_Float16)a[0]; o[1]=(_Float16)a[1]; o[2]=(_Float16)a[2]; o[3]=(_Float16)a[3];
        o[4]=(_Float16)b[0]; o[5]=(_Float16)b[1]; o[6]=(_Float16)b[2]; o[7]=(_Float16)b[3];
        xh[g] = o;
        int w0 = __builtin_amdgcn_cvt_pk_fp8_f32(a[0], a[1], 0, false);
        w0     = __builtin_amdgcn_cvt_pk_fp8_f32(a[2], a[3], w0, true);
        int w1 = __builtin_amdgcn_cvt_pk_fp8_f32(b[0], b[1], 0, false);
        w1     = __builtin_amdgcn_cvt_pk_fp8_f32(b[2], b[3], w1, true);
        uint2 p; p.x = (unsigned)w0; p.y = (unsigned)w1;
        x8[g] = p;
    }
}

// ---------------- weight packing: frag(kt,jt): lane holds W[kt*32+(l>>4)*8+r][jt*16+(l&15)]
__device__ inline void pack_one(const float* __restrict__ W, int C, _Float16* __restrict__ outp, int tid){
    int l = tid & 63;
    int f = tid >> 6;
    int NJT = C / 16;
    int kt = f / NJT;
    int jt = f - kt*NJT;
    int kbase = kt*32 + (l >> 4)*8;
    int col   = jt*16 + (l & 15);
    h8 o;
    #pragma unroll
    for (int r = 0; r < 8; ++r) o[r] = (_Float16)W[(kbase + r)*C + col];
    ((h8*)outp)[f*64 + l] = o;
}

__global__ void k_pack(const float* __restrict__ Wl1, const float* __restrict__ Wr1,
                       const float* __restrict__ Wl2, const float* __restrict__ Wr2,
                       _Float16* __restrict__ wl1p, _Float16* __restrict__ wr1p,
                       _Float16* __restrict__ wl2p, _Float16* __restrict__ wr2p){
    int tid = blockIdx.x*256 + threadIdx.x;
    if (tid < 2048)        pack_one(Wl1, 128, wl1p, tid);
    else if (tid < 4096)   pack_one(Wr1, 128, wr1p, tid - 2048);
    else if (tid < 5120)   pack_one(Wl2,  64, wl2p, tid - 4096);
    else if (tid < 6144)   pack_one(Wr2,  64, wr2p, tid - 5120);
}

// ---------------- aggregation 1: mean of x8 (128 fp8 = 32 u32) per node, fp16 out ----------------
// half-wave (32 lanes) per node; lane c owns fp8-u32 c (features 4c..4c+3); unroll-4 gathers
__global__ void k_agg1(const int* __restrict__ row_start, const int* __restrict__ csr,
                       const unsigned* __restrict__ x8, unsigned* __restrict__ mh32, int n){
    int node = (int)((blockIdx.x*(unsigned)blockDim.x + threadIdx.x) >> 5);
    int c = threadIdx.x & 31;
    if (node >= n) return;
    int base = row_start[node], end = row_start[node+1];
    int deg = end - base;
    f2 a0 = {0.f,0.f}, a1 = {0.f,0.f}, b0 = {0.f,0.f}, b1 = {0.f,0.f};
    f2 c0 = {0.f,0.f}, c1 = {0.f,0.f}, d0 = {0.f,0.f}, d1 = {0.f,0.f};
    int i = base;
    for (; i + 3 < end; i += 4){
        int e0 = csr[i], e1 = csr[i+1], e2 = csr[i+2], e3 = csr[i+3];
        unsigned v0 = x8[(size_t)e0*32 + c];
        unsigned v1 = x8[(size_t)e1*32 + c];
        unsigned v2 = x8[(size_t)e2*32 + c];
        unsigned v3 = x8[(size_t)e3*32 + c];
        a0 += __builtin_amdgcn_cvt_pk_f32_fp8(v0, false);
        a1 += __builtin_amdgcn_cvt_pk_f32_fp8(v0, true);
        b0 += __builtin_amdgcn_cvt_pk_f32_fp8(v1, false);
        b1 += __builtin_amdgcn_cvt_pk_f32_fp8(v1, true);
        c0 += __builtin_amdgcn_cvt_pk_f32_fp8(v2, false);
        c1 += __builtin_amdgcn_cvt_pk_f32_fp8(v2, true);
        d0 += __builtin_amdgcn_cvt_pk_f32_fp8(v3, false);
        d1 += __builtin_amdgcn_cvt_pk_f32_fp8(v3, true);
    }
    for (; i < end; ++i){
        int e = csr[i];
        unsigned v = x8[(size_t)e*32 + c];
        a0 += __builtin_amdgcn_cvt_pk_f32_fp8(v, false);
        a1 += __builtin_amdgcn_cvt_pk_f32_fp8(v, true);
    }
    a0 += b0 + c0 + d0;
    a1 += b1 + c1 + d1;
    float sc = 1.0f / (float)max(deg, 1);
    uint2 o;
    o.x = packh2(a0[0]*sc, a0[1]*sc);
    o.y = packh2(a1[0]*sc, a1[1]*sc);
    *(uint2*)(mh32 + (size_t)node*64 + 2*c) = o;
}

// ---------------- fused GEMM: H^T in-register, then P = H@Wl2 (f16) and Q = H@Wr2+b2 (f32 -> d_out)
__global__ __launch_bounds__(256, 4) void k_gemm_fused(
    const _Float16* __restrict__ A0,   // m1h [M][128] f16
    const _Float16* __restrict__ A1,   // xh  [M][128] f16
    const h8* __restrict__ B0,         // wl1p frags
    const h8* __restrict__ B1,         // wr1p frags
    const float* __restrict__ bias1,
    const h8* __restrict__ W2l,        // wl2p frags
    const h8* __restrict__ W2r,        // wr2p frags
    const float* __restrict__ bias2,
    _Float16* __restrict__ P,          // [M][64] f16
    float* __restrict__ Q,             // [M][64] f32 (aliases d_out)
    int M)
{
    int wid = threadIdx.x >> 6, lane = threadIdx.x & 63;
    int m0 = (blockIdx.x*4 + wid) * 16;
    if (m0 >= M) return;
    int m = lane & 15, kg = lane >> 4;
    int rowc = min(m0 + m, M-1);

    f4 acc[8];
    #pragma unroll
    for (int j = 0; j < 8; ++j) acc[j] = (f4)0.0f;

    #pragma unroll
    for (int ph = 0; ph < 2; ++ph){
        const _Float16* A = ph ? A1 : A0;
        const h8* B = ph ? B1 : B0;
        #pragma unroll
        for (int kt = 0; kt < 4; ++kt){
            h8 nf = *(const h8*)(A + (size_t)rowc*128 + kt*32 + kg*8);
            #pragma unroll
            for (int j = 0; j < 8; ++j){
                h8 wf = B[(kt*8 + j)*64 + lane];
                acc[j] = __builtin_amdgcn_mfma_f32_16x16x32_f16(wf, nf, acc[j], 0, 0, 0);
            }
        }
    }

    unsigned hreg[16];
    #pragma unroll
    for (int j = 0; j < 8; ++j){
        f4 bb = *(const f4*)(bias1 + j*16 + kg*4);
        float v0 = acc[j][0] + bb[0]; v0 = v0 > 0.f ? v0 : 0.f;
        float v1 = acc[j][1] + bb[1]; v1 = v1 > 0.f ? v1 : 0.f;
        float v2 = acc[j][2] + bb[2]; v2 = v2 > 0.f ? v2 : 0.f;
        float v3 = acc[j][3] + bb[3]; v3 = v3 > 0.f ? v3 : 0.f;
        hreg[2*j]   = packh2(v0, v1);
        hreg[2*j+1] = packh2(v2, v3);
    }

    f4 accP[4], accQ[4];
    #pragma unroll
    for (int j = 0; j < 4; ++j){ accP[j] = (f4)0.0f; accQ[j] = (f4)0.0f; }

    int srcA = ((kg & 1) * 2) * 16 + m;
    int srcB = srcA + 16;
    bool hi = (kg >> 1) & 1;

    #pragma unroll
    for (int kt = 0; kt < 4; ++kt){
        unsigned sA0 = (unsigned)__shfl((int)hreg[4*kt+0], srcA, 64);
        unsigned sA1 = (unsigned)__shfl((int)hreg[4*kt+1], srcA, 64);
        unsigned sA2 = (unsigned)__shfl((int)hreg[4*kt+2], srcA, 64);
        unsigned sA3 = (unsigned)__shfl((int)hreg[4*kt+3], srcA, 64);
        unsigned sB0 = (unsigned)__shfl((int)hreg[4*kt+0], srcB, 64);
        unsigned sB1 = (unsigned)__shfl((int)hreg[4*kt+1], srcB, 64);
        unsigned sB2 = (unsigned)__shfl((int)hreg[4*kt+2], srcB, 64);
        unsigned sB3 = (unsigned)__shfl((int)hreg[4*kt+3], srcB, 64);
        u4 u;
        u[0] = hi ? sA2 : sA0;
        u[1] = hi ? sA3 : sA1;
        u[2] = hi ? sB2 : sB0;
        u[3] = hi ? sB3 : sB1;
        h8 hf = __builtin_bit_cast(h8, u);
        #pragma unroll
        for (int j2 = 0; j2 < 4; ++j2){
            accP[j2] = __builtin_amdgcn_mfma_f32_16x16x32_f16(W2l[(kt*4 + j2)*64 + lane], hf, accP[j2], 0, 0, 0);
            accQ[j2] = __builtin_amdgcn_mfma_f32_16x16x32_f16(W2r[(kt*4 + j2)*64 + lane], hf, accQ[j2], 0, 0, 0);
        }
    }

    int node = m0 + m;
    if (node < M){
        #pragma unroll
        for (int j2 = 0; j2 < 4; ++j2){
            int f = j2*16 + kg*4;
            unsigned p0 = packh2(accP[j2][0], accP[j2][1]);
            unsigned p1 = packh2(accP[j2][2], accP[j2][3]);
            uint2 pv; pv.x = p0; pv.y = p1;
            *(uint2*)((unsigned short*)P + (size_t)node*64 + f) = pv;
            f4 bb2 = *(const f4*)(bias2 + f);
            f4 qv;
            qv[0] = accQ[j2][0] + bb2[0];
            qv[1] = accQ[j2][1] + bb2[1];
            qv[2] = accQ[j2][2] + bb2[2];
            qv[3] = accQ[j2][3] + bb2[3];
            *(f4*)(Q + (size_t)node*64 + f) = qv;
        }
    }
}

// ---------------- aggregation 2 fused: out = Q + mean-gather(P) ----------------
// half-wave (32 lanes) per node; lane c owns f16-pair-u32 c (features 2c,2c+1); unroll-4 gathers
__global__ void k_agg2f(const int* __restrict__ row_start, const int* __restrict__ csr,
                        const unsigned* __restrict__ ph32, const float* __restrict__ Q,
                        float* __restrict__ out, int n){
    int node = (int)((blockIdx.x*(unsigned)blockDim.x + threadIdx.x) >> 5);
    int c = threadIdx.x & 31;
    if (node >= n) return;
    int base = row_start[node], end = row_start[node+1];
    int deg = end - base;
    float a0=0,a1=0,b0=0,b1=0,c0=0,c1=0,d0=0,d1=0;
    int i = base;
    for (; i + 3 < end; i += 4){
        int e0 = csr[i], e1 = csr[i+1], e2 = csr[i+2], e3 = csr[i+3];
        unsigned v0 = ph32[(size_t)e0*32 + c];
        unsigned v1 = ph32[(size_t)e1*32 + c];
        unsigned v2 = ph32[(size_t)e2*32 + c];
        unsigned v3 = ph32[(size_t)e3*32 + c];
        a0 += h2lo(v0); a1 += h2hi(v0);
        b0 += h2lo(v1); b1 += h2hi(v1);
        c0 += h2lo(v2); c1 += h2hi(v2);
        d0 += h2lo(v3); d1 += h2hi(v3);
    }
    for (; i < end; ++i){
        int e = csr[i];
        unsigned v = ph32[(size_t)e*32 + c];
        a0 += h2lo(v); a1 += h2hi(v);
    }
    a0 = (a0 + b0) + (c0 + d0);
    a1 = (a1 + b1) + (c1 + d1);
    float sc = 1.0f / (float)max(deg, 1);
    const float2 q = *(const float2*)(Q + (size_t)node*64 + 2*c);
    float2 o;
    o.x = a0*sc + q.x;
    o.y = a1*sc + q.y;
    *(float2*)(out + (size_t)node*64 + 2*c) = o;
}

extern "C" void kernel_launch(void* const* d_in, const int* in_sizes, int n_in,
                              void* d_out, int out_size, void* d_ws, size_t ws_size,
                              hipStream_t stream) {
    const float* x   = (const float*)d_in[0];
    const int*   ei  = (const int*)d_in[1];
    const float* Wl1 = (const float*)d_in[2];
    const float* bl1 = (const float*)d_in[3];
    const float* Wr1 = (const float*)d_in[4];
    const float* Wl2 = (const float*)d_in[5];
    const float* bl2 = (const float*)d_in[6];
    const float* Wr2 = (const float*)d_in[7];

    const int N = in_sizes[0] / IN_C;
    const int E = in_sizes[1] / 2;
    const int* src = ei;
    const int* dst = ei + E;

    const int NBLK = (E + EPB - 1) / EPB;
    const int n_s  = NBUCK * NBLK;

    char* w = (char*)d_ws;
    size_t off = 0;
    auto alloc = [&](size_t bytes) -> char* {
        char* p = w + off;
        off = (off + bytes + 255) & ~(size_t)255;
        return p;
    };
    int* histT      = (int*)alloc((size_t)n_s*4);
    int* tmp        = (int*)alloc((size_t)n_s*4);
    int* bsum       = (int*)alloc(4096);
    unsigned* sorted= (unsigned*)alloc((size_t)E*4);
    int* csr        = (int*)alloc((size_t)E*4);
    int* row_start  = (int*)alloc((size_t)(N+1)*4);
    _Float16* xh    = (_Float16*)alloc((size_t)N*IN_C*2);
    unsigned* x8    = (unsigned*)alloc((size_t)N*IN_C);
    _Float16* m1h   = (_Float16*)alloc((size_t)N*IN_C*2);
    _Float16* ph    = (_Float16*)alloc((size_t)N*OUT_C*2);
    _Float16* wl1p  = (_Float16*)alloc(4*8*64*8*2);
    _Float16* wr1p  = (_Float16*)alloc(4*8*64*8*2);
    _Float16* wl2p  = (_Float16*)alloc(4*4*64*8*2);
    _Float16* wr2p  = (_Float16*)alloc(4*4*64*8*2);

    const int SB = (n_s + 255) / 256;

    k_hist   <<<NBLK, 256, 0, stream>>>(dst, E, histT, NBLK);
    k_scanA  <<<SB, 256, 0, stream>>>(histT, tmp, bsum, n_s);
    k_scanB  <<<1, 1024, 0, stream>>>(bsum, SB);
    k_scatter<<<NBLK, 256, 0, stream>>>(src, dst, E, tmp, bsum, NBLK, sorted);
    k_csr    <<<NBUCK, 512, 0, stream>>>(sorted, tmp, bsum, NBLK, E, N, csr, row_start);

    const int n8 = N*IN_C/8;
    k_cvt<<<(n8 + 255)/256, 256, 0, stream>>>(x, (h8*)xh, (uint2*)x8, n8);
    k_pack<<<24, 256, 0, stream>>>(Wl1, Wr1, Wl2, Wr2, wl1p, wr1p, wl2p, wr2p);

    // half-wave (32 lanes) per node
    const int AB = (N + 7) / 8;      // N*32 threads / 256
    k_agg1<<<AB, 256, 0, stream>>>(row_start, csr, x8, (unsigned*)m1h, N);

    float* Q = (float*)d_out;
    const int GB2 = (N + 63)/64;
    k_gemm_fused<<<GB2, 256, 0, stream>>>(m1h, xh, (const h8*)wl1p, (const h8*)wr1p, bl1,
                                          (const h8*)wl2p, (const h8*)wr2p, bl2,
                                          ph, Q, N);

    k_agg2f<<<AB, 256, 0, stream>>>(row_start, csr, (const unsigned*)ph, Q, (float*)d_out, N);
}

// Round 6
// 187.555 us; speedup vs baseline: 2.3970x; 1.0976x over previous
//
#include <hip/hip_runtime.h>
#include <hip/hip_bf16.h>
#include <stdint.h>

#define IN_C 128
#define HID_C 128
#define OUT_C 64

#define NBUCK 256
#define BSH 9
#define EPB 4096

typedef _Float16 h8 __attribute__((ext_vector_type(8)));
typedef _Float16 h2 __attribute__((ext_vector_type(2)));
typedef float f4 __attribute__((ext_vector_type(4)));
typedef float f2 __attribute__((ext_vector_type(2)));
typedef unsigned u4 __attribute__((ext_vector_type(4)));

__device__ inline float h2lo(unsigned v){ h2 t = __builtin_bit_cast(h2, v); return (float)t[0]; }
__device__ inline float h2hi(unsigned v){ h2 t = __builtin_bit_cast(h2, v); return (float)t[1]; }
__device__ inline unsigned packh2(float a, float b){ h2 t; t[0]=(_Float16)a; t[1]=(_Float16)b; return __builtin_bit_cast(unsigned, t); }

// ---------------- CSR build: atomic-free counting sort ----------------
__global__ __launch_bounds__(256) void k_hist(const int* __restrict__ dst, int E,
                                              int* __restrict__ histT, int NBLK){
    __shared__ int h[NBUCK];
    int t = threadIdx.x;
    h[t] = 0; __syncthreads();
    int e0 = blockIdx.x*EPB, e1 = min(E, e0 + EPB);
    for (int e = e0 + t; e < e1; e += 256) atomicAdd(&h[((unsigned)dst[e]) >> BSH], 1);
    __syncthreads();
    histT[t*NBLK + blockIdx.x] = h[t];
}

__global__ void k_scanA(const int* __restrict__ cnt, int* __restrict__ tmp, int* __restrict__ bsum, int n){
    __shared__ int s[256];
    int t = threadIdx.x, g = blockIdx.x*256 + t;
    int v = (g < n) ? cnt[g] : 0;
    s[t] = v; __syncthreads();
    for (int off = 1; off < 256; off <<= 1){
        int a = (t >= off) ? s[t-off] : 0;
        __syncthreads();
        s[t] += a;
        __syncthreads();
    }
    int excl = (t == 0) ? 0 : s[t-1];
    if (g < n) tmp[g] = excl;
    if (t == 255) bsum[blockIdx.x] = s[255];
}

__global__ void k_scanB(int* __restrict__ bsum, int nb){
    __shared__ int s[1024];
    int t = threadIdx.x;
    int v = (t < nb) ? bsum[t] : 0;
    s[t] = v; __syncthreads();
    for (int off = 1; off < 1024; off <<= 1){
        int a = (t >= off) ? s[t-off] : 0;
        __syncthreads();
        s[t] += a;
        __syncthreads();
    }
    int excl = (t == 0) ? 0 : s[t-1];
    if (t < nb) bsum[t] = excl;
}

// S[g] = tmp[g] + bsum[g>>8], computed on the fly by consumers
__global__ __launch_bounds__(256) void k_scatter(const int* __restrict__ src, const int* __restrict__ dst,
                                                 int E, const int* __restrict__ tmp, const int* __restrict__ bsum,
                                                 int NBLK, unsigned* __restrict__ sorted){
    __shared__ int off[NBUCK];
    int t = threadIdx.x;
    int g = t*NBLK + blockIdx.x;
    off[t] = tmp[g] + bsum[g >> 8];
    __syncthreads();
    int e0 = blockIdx.x*EPB, e1 = min(E, e0 + EPB);
    for (int e = e0 + t; e < e1; e += 256){
        int d = dst[e];
        int b = ((unsigned)d) >> BSH;
        int p = atomicAdd(&off[b], 1);
        sorted[p] = (unsigned)src[e] | (((unsigned)(d & ((1<<BSH)-1))) << 17);
    }
}

__global__ __launch_bounds__(512) void k_csr(const unsigned* __restrict__ sorted,
                                             const int* __restrict__ tmp, const int* __restrict__ bsum,
                                             int NBLK, int E, int N,
                                             int* __restrict__ csr, int* __restrict__ row_start){
    __shared__ int cnt[512];
    __shared__ int sc[512];
    int b = blockIdx.x, t = threadIdx.x;
    int i0 = b*NBLK;
    int bs = tmp[i0] + bsum[i0 >> 8];
    int be = (b == NBUCK-1) ? E : (tmp[i0 + NBLK] + bsum[(i0 + NBLK) >> 8]);
    cnt[t] = 0; __syncthreads();
    for (int e = bs + t; e < be; e += 512) atomicAdd(&cnt[sorted[e] >> 17], 1);
    __syncthreads();
    sc[t] = cnt[t]; __syncthreads();
    for (int off = 1; off < 512; off <<= 1){
        int a = (t >= off) ? sc[t-off] : 0;
        __syncthreads();
        sc[t] += a;
        __syncthreads();
    }
    int excl = sc[t] - cnt[t];
    int nid = (b << BSH) + t;
    if (nid < N) row_start[nid] = bs + excl;
    if (t == 0 && b == (N >> BSH)) row_start[N] = E;
    __syncthreads();
    cnt[t] = excl;
    __syncthreads();
    for (int e = bs + t; e < be; e += 512){
        unsigned v = sorted[e];
        int dl = v >> 17;
        int p = atomicAdd(&cnt[dl], 1);
        csr[bs + p] = (int)(v & 0x1FFFFu);
    }
}

// ---------------- fp32 -> fp16 + fp8 conversion ----------------
__global__ void k_cvt(const float* __restrict__ x, h8* __restrict__ xh, uint2* __restrict__ x8, int n8){
    int g = blockIdx.x*256 + threadIdx.x;
    if (g < n8){
        const f4* xp = (const f4*)(x + (size_t)g*8);
        f4 a = xp[0], b = xp[1];
        h8 o;
        o[0]=(_Float16)a[0]; o[1]=(_Float16)a[1]; o[2]=(_Float16)a[2]; o[3]=(_Float16)a[3];
        o[4]=(_Float16)b[0]; o[5]=(_Float16)b[1]; o[6]=(_Float16)b[2]; o[7]=(_Float16)b[3];
        xh[g] = o;
        int w0 = __builtin_amdgcn_cvt_pk_fp8_f32(a[0], a[1], 0, false);
        w0     = __builtin_amdgcn_cvt_pk_fp8_f32(a[2], a[3], w0, true);
        int w1 = __builtin_amdgcn_cvt_pk_fp8_f32(b[0], b[1], 0, false);
        w1     = __builtin_amdgcn_cvt_pk_fp8_f32(b[2], b[3], w1, true);
        uint2 p; p.x = (unsigned)w0; p.y = (unsigned)w1;
        x8[g] = p;
    }
}

// ---------------- weight packing: frag(kt,jt): lane holds W[kt*32+(l>>4)*8+r][jt*16+(l&15)]
__device__ inline void pack_one(const float* __restrict__ W, int C, _Float16* __restrict__ outp, int tid){
    int l = tid & 63;
    int f = tid >> 6;
    int NJT = C / 16;
    int kt = f / NJT;
    int jt = f - kt*NJT;
    int kbase = kt*32 + (l >> 4)*8;
    int col   = jt*16 + (l & 15);
    h8 o;
    #pragma unroll
    for (int r = 0; r < 8; ++r) o[r] = (_Float16)W[(kbase + r)*C + col];
    ((h8*)outp)[f*64 + l] = o;
}

__global__ void k_pack(const float* __restrict__ Wl1, const float* __restrict__ Wr1,
                       const float* __restrict__ Wl2, const float* __restrict__ Wr2,
                       _Float16* __restrict__ wl1p, _Float16* __restrict__ wr1p,
                       _Float16* __restrict__ wl2p, _Float16* __restrict__ wr2p){
    int tid = blockIdx.x*256 + threadIdx.x;
    if (tid < 2048)        pack_one(Wl1, 128, wl1p, tid);
    else if (tid < 4096)   pack_one(Wr1, 128, wr1p, tid - 2048);
    else if (tid < 5120)   pack_one(Wl2,  64, wl2p, tid - 4096);
    else if (tid < 6144)   pack_one(Wr2,  64, wr2p, tid - 5120);
}

// ---------------- aggregation 1: half-wave per node, fp8 gather, unroll-4 ----------------
__global__ void k_agg1(const int* __restrict__ row_start, const int* __restrict__ csr,
                       const unsigned* __restrict__ x8, unsigned* __restrict__ mh32, int n){
    int node = (int)((blockIdx.x*(unsigned)blockDim.x + threadIdx.x) >> 5);
    int c = threadIdx.x & 31;
    if (node >= n) return;
    int base = row_start[node], end = row_start[node+1];
    int deg = end - base;
    f2 a0 = {0.f,0.f}, a1 = {0.f,0.f}, b0 = {0.f,0.f}, b1 = {0.f,0.f};
    f2 c0 = {0.f,0.f}, c1 = {0.f,0.f}, d0 = {0.f,0.f}, d1 = {0.f,0.f};
    int i = base;
    for (; i + 3 < end; i += 4){
        int e0 = csr[i], e1 = csr[i+1], e2 = csr[i+2], e3 = csr[i+3];
        unsigned v0 = x8[(size_t)e0*32 + c];
        unsigned v1 = x8[(size_t)e1*32 + c];
        unsigned v2 = x8[(size_t)e2*32 + c];
        unsigned v3 = x8[(size_t)e3*32 + c];
        a0 += __builtin_amdgcn_cvt_pk_f32_fp8(v0, false);
        a1 += __builtin_amdgcn_cvt_pk_f32_fp8(v0, true);
        b0 += __builtin_amdgcn_cvt_pk_f32_fp8(v1, false);
        b1 += __builtin_amdgcn_cvt_pk_f32_fp8(v1, true);
        c0 += __builtin_amdgcn_cvt_pk_f32_fp8(v2, false);
        c1 += __builtin_amdgcn_cvt_pk_f32_fp8(v2, true);
        d0 += __builtin_amdgcn_cvt_pk_f32_fp8(v3, false);
        d1 += __builtin_amdgcn_cvt_pk_f32_fp8(v3, true);
    }
    for (; i < end; ++i){
        int e = csr[i];
        unsigned v = x8[(size_t)e*32 + c];
        a0 += __builtin_amdgcn_cvt_pk_f32_fp8(v, false);
        a1 += __builtin_amdgcn_cvt_pk_f32_fp8(v, true);
    }
    a0 += b0 + c0 + d0;
    a1 += b1 + c1 + d1;
    float sc = 1.0f / (float)max(deg, 1);
    uint2 o;
    o.x = packh2(a0[0]*sc, a0[1]*sc);
    o.y = packh2(a1[0]*sc, a1[1]*sc);
    *(uint2*)(mh32 + (size_t)node*64 + 2*c) = o;
}

// ---------------- fused GEMM: layer-1 weights LDS-staged; H^T in-register; layer 2 fused ----------------
__global__ __launch_bounds__(256, 2) void k_gemm_fused(
    const _Float16* __restrict__ A0,   // m1h [M][128] f16
    const _Float16* __restrict__ A1,   // xh  [M][128] f16
    const h8* __restrict__ B0,         // wl1p frags (2048 h8)
    const h8* __restrict__ B1,         // wr1p frags (2048 h8)
    const float* __restrict__ bias1,
    const h8* __restrict__ W2l,        // wl2p frags
    const h8* __restrict__ W2r,        // wr2p frags
    const float* __restrict__ bias2,
    _Float16* __restrict__ P,          // [M][64] f16
    float* __restrict__ Q,             // [M][64] f32 (aliases d_out)
    int M)
{
    __shared__ h8 shB[4096];           // 64 KB: [0..2047]=wl1p, [2048..4095]=wr1p
    int tid = threadIdx.x;
    #pragma unroll
    for (int i = 0; i < 8; ++i) shB[i*256 + tid] = B0[i*256 + tid];
    #pragma unroll
    for (int i = 0; i < 8; ++i) shB[2048 + i*256 + tid] = B1[i*256 + tid];
    __syncthreads();

    int wid = tid >> 6, lane = tid & 63;
    int m0 = (blockIdx.x*4 + wid) * 16;
    if (m0 >= M) return;
    int m = lane & 15, kg = lane >> 4;
    int rowc = min(m0 + m, M-1);

    f4 acc[8];
    #pragma unroll
    for (int j = 0; j < 8; ++j) acc[j] = (f4)0.0f;

    #pragma unroll
    for (int ph = 0; ph < 2; ++ph){
        const _Float16* A = ph ? A1 : A0;
        #pragma unroll
        for (int kt = 0; kt < 4; ++kt){
            h8 nf = *(const h8*)(A + (size_t)rowc*128 + kt*32 + kg*8);
            #pragma unroll
            for (int j = 0; j < 8; ++j){
                h8 wf = shB[ph*2048 + (kt*8 + j)*64 + lane];
                acc[j] = __builtin_amdgcn_mfma_f32_16x16x32_f16(wf, nf, acc[j], 0, 0, 0);
            }
        }
    }

    unsigned hreg[16];
    #pragma unroll
    for (int j = 0; j < 8; ++j){
        f4 bb = *(const f4*)(bias1 + j*16 + kg*4);
        float v0 = acc[j][0] + bb[0]; v0 = v0 > 0.f ? v0 : 0.f;
        float v1 = acc[j][1] + bb[1]; v1 = v1 > 0.f ? v1 : 0.f;
        float v2 = acc[j][2] + bb[2]; v2 = v2 > 0.f ? v2 : 0.f;
        float v3 = acc[j][3] + bb[3]; v3 = v3 > 0.f ? v3 : 0.f;
        hreg[2*j]   = packh2(v0, v1);
        hreg[2*j+1] = packh2(v2, v3);
    }

    f4 accP[4], accQ[4];
    #pragma unroll
    for (int j = 0; j < 4; ++j){ accP[j] = (f4)0.0f; accQ[j] = (f4)0.0f; }

    int srcA = ((kg & 1) * 2) * 16 + m;
    int srcB = srcA + 16;
    bool hi = (kg >> 1) & 1;

    #pragma unroll
    for (int kt = 0; kt < 4; ++kt){
        unsigned sA0 = (unsigned)__shfl((int)hreg[4*kt+0], srcA, 64);
        unsigned sA1 = (unsigned)__shfl((int)hreg[4*kt+1], srcA, 64);
        unsigned sA2 = (unsigned)__shfl((int)hreg[4*kt+2], srcA, 64);
        unsigned sA3 = (unsigned)__shfl((int)hreg[4*kt+3], srcA, 64);
        unsigned sB0 = (unsigned)__shfl((int)hreg[4*kt+0], srcB, 64);
        unsigned sB1 = (unsigned)__shfl((int)hreg[4*kt+1], srcB, 64);
        unsigned sB2 = (unsigned)__shfl((int)hreg[4*kt+2], srcB, 64);
        unsigned sB3 = (unsigned)__shfl((int)hreg[4*kt+3], srcB, 64);
        u4 u;
        u[0] = hi ? sA2 : sA0;
        u[1] = hi ? sA3 : sA1;
        u[2] = hi ? sB2 : sB0;
        u[3] = hi ? sB3 : sB1;
        h8 hf = __builtin_bit_cast(h8, u);
        #pragma unroll
        for (int j2 = 0; j2 < 4; ++j2){
            accP[j2] = __builtin_amdgcn_mfma_f32_16x16x32_f16(W2l[(kt*4 + j2)*64 + lane], hf, accP[j2], 0, 0, 0);
            accQ[j2] = __builtin_amdgcn_mfma_f32_16x16x32_f16(W2r[(kt*4 + j2)*64 + lane], hf, accQ[j2], 0, 0, 0);
        }
    }

    int node = m0 + m;
    if (node < M){
        #pragma unroll
        for (int j2 = 0; j2 < 4; ++j2){
            int f = j2*16 + kg*4;
            unsigned p0 = packh2(accP[j2][0], accP[j2][1]);
            unsigned p1 = packh2(accP[j2][2], accP[j2][3]);
            uint2 pv; pv.x = p0; pv.y = p1;
            *(uint2*)((unsigned short*)P + (size_t)node*64 + f) = pv;
            f4 bb2 = *(const f4*)(bias2 + f);
            f4 qv;
            qv[0] = accQ[j2][0] + bb2[0];
            qv[1] = accQ[j2][1] + bb2[1];
            qv[2] = accQ[j2][2] + bb2[2];
            qv[3] = accQ[j2][3] + bb2[3];
            *(f4*)(Q + (size_t)node*64 + f) = qv;
        }
    }
}

// ---------------- aggregation 2 fused: out = Q + mean-gather(P); half-wave per node ----------------
__global__ void k_agg2f(const int* __restrict__ row_start, const int* __restrict__ csr,
                        const unsigned* __restrict__ ph32, const float* __restrict__ Q,
                        float* __restrict__ out, int n){
    int node = (int)((blockIdx.x*(unsigned)blockDim.x + threadIdx.x) >> 5);
    int c = threadIdx.x & 31;
    if (node >= n) return;
    int base = row_start[node], end = row_start[node+1];
    int deg = end - base;
    float a0=0,a1=0,b0=0,b1=0,c0=0,c1=0,d0=0,d1=0;
    int i = base;
    for (; i + 3 < end; i += 4){
        int e0 = csr[i], e1 = csr[i+1], e2 = csr[i+2], e3 = csr[i+3];
        unsigned v0 = ph32[(size_t)e0*32 + c];
        unsigned v1 = ph32[(size_t)e1*32 + c];
        unsigned v2 = ph32[(size_t)e2*32 + c];
        unsigned v3 = ph32[(size_t)e3*32 + c];
        a0 += h2lo(v0); a1 += h2hi(v0);
        b0 += h2lo(v1); b1 += h2hi(v1);
        c0 += h2lo(v2); c1 += h2hi(v2);
        d0 += h2lo(v3); d1 += h2hi(v3);
    }
    for (; i < end; ++i){
        int e = csr[i];
        unsigned v = ph32[(size_t)e*32 + c];
        a0 += h2lo(v); a1 += h2hi(v);
    }
    a0 = (a0 + b0) + (c0 + d0);
    a1 = (a1 + b1) + (c1 + d1);
    float sc = 1.0f / (float)max(deg, 1);
    const float2 q = *(const float2*)(Q + (size_t)node*64 + 2*c);
    float2 o;
    o.x = a0*sc + q.x;
    o.y = a1*sc + q.y;
    *(float2*)(out + (size_t)node*64 + 2*c) = o;
}

extern "C" void kernel_launch(void* const* d_in, const int* in_sizes, int n_in,
                              void* d_out, int out_size, void* d_ws, size_t ws_size,
                              hipStream_t stream) {
    const float* x   = (const float*)d_in[0];
    const int*   ei  = (const int*)d_in[1];
    const float* Wl1 = (const float*)d_in[2];
    const float* bl1 = (const float*)d_in[3];
    const float* Wr1 = (const float*)d_in[4];
    const float* Wl2 = (const float*)d_in[5];
    const float* bl2 = (const float*)d_in[6];
    const float* Wr2 = (const float*)d_in[7];

    const int N = in_sizes[0] / IN_C;
    const int E = in_sizes[1] / 2;
    const int* src = ei;
    const int* dst = ei + E;

    const int NBLK = (E + EPB - 1) / EPB;
    const int n_s  = NBUCK * NBLK;

    char* w = (char*)d_ws;
    size_t off = 0;
    auto alloc = [&](size_t bytes) -> char* {
        char* p = w + off;
        off = (off + bytes + 255) & ~(size_t)255;
        return p;
    };
    int* histT      = (int*)alloc((size_t)n_s*4);
    int* tmp        = (int*)alloc((size_t)n_s*4);
    int* bsum       = (int*)alloc(4096);
    unsigned* sorted= (unsigned*)alloc((size_t)E*4);
    int* csr        = (int*)alloc((size_t)E*4);
    int* row_start  = (int*)alloc((size_t)(N+1)*4);
    _Float16* xh    = (_Float16*)alloc((size_t)N*IN_C*2);
    unsigned* x8    = (unsigned*)alloc((size_t)N*IN_C);
    _Float16* m1h   = (_Float16*)alloc((size_t)N*IN_C*2);
    _Float16* ph    = (_Float16*)alloc((size_t)N*OUT_C*2);
    _Float16* wl1p  = (_Float16*)alloc(4*8*64*8*2);
    _Float16* wr1p  = (_Float16*)alloc(4*8*64*8*2);
    _Float16* wl2p  = (_Float16*)alloc(4*4*64*8*2);
    _Float16* wr2p  = (_Float16*)alloc(4*4*64*8*2);

    const int SB = (n_s + 255) / 256;

    k_hist   <<<NBLK, 256, 0, stream>>>(dst, E, histT, NBLK);
    k_scanA  <<<SB, 256, 0, stream>>>(histT, tmp, bsum, n_s);
    k_scanB  <<<1, 1024, 0, stream>>>(bsum, SB);
    k_scatter<<<NBLK, 256, 0, stream>>>(src, dst, E, tmp, bsum, NBLK, sorted);
    k_csr    <<<NBUCK, 512, 0, stream>>>(sorted, tmp, bsum, NBLK, E, N, csr, row_start);

    const int n8 = N*IN_C/8;
    k_cvt<<<(n8 + 255)/256, 256, 0, stream>>>(x, (h8*)xh, (uint2*)x8, n8);
    k_pack<<<24, 256, 0, stream>>>(Wl1, Wr1, Wl2, Wr2, wl1p, wr1p, wl2p, wr2p);

    const int AB = (N + 7) / 8;      // half-wave per node
    k_agg1<<<AB, 256, 0, stream>>>(row_start, csr, x8, (unsigned*)m1h, N);

    float* Q = (float*)d_out;
    const int GB2 = (N + 63)/64;
    k_gemm_fused<<<GB2, 256, 0, stream>>>(m1h, xh, (const h8*)wl1p, (const h8*)wr1p, bl1,
                                          (const h8*)wl2p, (const h8*)wr2p, bl2,
                                          ph, Q, N);

    k_agg2f<<<AB, 256, 0, stream>>>(row_start, csr, (const unsigned*)ph, Q, (float*)d_out, N);
}

// Round 7
// 159.771 us; speedup vs baseline: 2.8138x; 1.1739x over previous
//
#include <hip/hip_runtime.h>
#include <hip/hip_bf16.h>
#include <stdint.h>

#define IN_C 128
#define HID_C 128
#define OUT_C 64

#define NBUCK 256
#define BSH 9
#define EPB 4096

typedef _Float16 h8 __attribute__((ext_vector_type(8)));
typedef _Float16 h2 __attribute__((ext_vector_type(2)));
typedef float f4 __attribute__((ext_vector_type(4)));
typedef float f2 __attribute__((ext_vector_type(2)));
typedef unsigned u4 __attribute__((ext_vector_type(4)));

__device__ inline float h2lo(unsigned v){ h2 t = __builtin_bit_cast(h2, v); return (float)t[0]; }
__device__ inline float h2hi(unsigned v){ h2 t = __builtin_bit_cast(h2, v); return (float)t[1]; }
__device__ inline unsigned packh2(float a, float b){ h2 t; t[0]=(_Float16)a; t[1]=(_Float16)b; return __builtin_bit_cast(unsigned, t); }

// ---------------- CSR build: atomic-free counting sort ----------------
__global__ __launch_bounds__(256) void k_hist(const int* __restrict__ dst, int E,
                                              int* __restrict__ histT, int NBLK){
    __shared__ int h[NBUCK];
    int t = threadIdx.x;
    h[t] = 0; __syncthreads();
    int e0 = blockIdx.x*EPB, e1 = min(E, e0 + EPB);
    for (int e = e0 + t; e < e1; e += 256) atomicAdd(&h[((unsigned)dst[e]) >> BSH], 1);
    __syncthreads();
    histT[t*NBLK + blockIdx.x] = h[t];
}

__global__ void k_scanA(const int* __restrict__ cnt, int* __restrict__ tmp, int* __restrict__ bsum, int n){
    __shared__ int s[256];
    int t = threadIdx.x, g = blockIdx.x*256 + t;
    int v = (g < n) ? cnt[g] : 0;
    s[t] = v; __syncthreads();
    for (int off = 1; off < 256; off <<= 1){
        int a = (t >= off) ? s[t-off] : 0;
        __syncthreads();
        s[t] += a;
        __syncthreads();
    }
    int excl = (t == 0) ? 0 : s[t-1];
    if (g < n) tmp[g] = excl;
    if (t == 255) bsum[blockIdx.x] = s[255];
}

__global__ void k_scanB(int* __restrict__ bsum, int nb){
    __shared__ int s[1024];
    int t = threadIdx.x;
    int v = (t < nb) ? bsum[t] : 0;
    s[t] = v; __syncthreads();
    for (int off = 1; off < 1024; off <<= 1){
        int a = (t >= off) ? s[t-off] : 0;
        __syncthreads();
        s[t] += a;
        __syncthreads();
    }
    int excl = (t == 0) ? 0 : s[t-1];
    if (t < nb) bsum[t] = excl;
}

// S[g] = tmp[g] + bsum[g>>8], computed on the fly by consumers
__global__ __launch_bounds__(256) void k_scatter(const int* __restrict__ src, const int* __restrict__ dst,
                                                 int E, const int* __restrict__ tmp, const int* __restrict__ bsum,
                                                 int NBLK, unsigned* __restrict__ sorted){
    __shared__ int off[NBUCK];
    int t = threadIdx.x;
    int g = t*NBLK + blockIdx.x;
    off[t] = tmp[g] + bsum[g >> 8];
    __syncthreads();
    int e0 = blockIdx.x*EPB, e1 = min(E, e0 + EPB);
    for (int e = e0 + t; e < e1; e += 256){
        int d = dst[e];
        int b = ((unsigned)d) >> BSH;
        int p = atomicAdd(&off[b], 1);
        sorted[p] = (unsigned)src[e] | (((unsigned)(d & ((1<<BSH)-1))) << 17);
    }
}

__global__ __launch_bounds__(512) void k_csr(const unsigned* __restrict__ sorted,
                                             const int* __restrict__ tmp, const int* __restrict__ bsum,
                                             int NBLK, int E, int N,
                                             int* __restrict__ csr, int* __restrict__ row_start){
    __shared__ int cnt[512];
    __shared__ int sc[512];
    int b = blockIdx.x, t = threadIdx.x;
    int i0 = b*NBLK;
    int bs = tmp[i0] + bsum[i0 >> 8];
    int be = (b == NBUCK-1) ? E : (tmp[i0 + NBLK] + bsum[(i0 + NBLK) >> 8]);
    cnt[t] = 0; __syncthreads();
    for (int e = bs + t; e < be; e += 512) atomicAdd(&cnt[sorted[e] >> 17], 1);
    __syncthreads();
    sc[t] = cnt[t]; __syncthreads();
    for (int off = 1; off < 512; off <<= 1){
        int a = (t >= off) ? sc[t-off] : 0;
        __syncthreads();
        sc[t] += a;
        __syncthreads();
    }
    int excl = sc[t] - cnt[t];
    int nid = (b << BSH) + t;
    if (nid < N) row_start[nid] = bs + excl;
    if (t == 0 && b == (N >> BSH)) row_start[N] = E;
    __syncthreads();
    cnt[t] = excl;
    __syncthreads();
    for (int e = bs + t; e < be; e += 512){
        unsigned v = sorted[e];
        int dl = v >> 17;
        int p = atomicAdd(&cnt[dl], 1);
        csr[bs + p] = (int)(v & 0x1FFFFu);
    }
}

// ---------------- fp32 -> fp16 + fp8 conversion ----------------
__global__ void k_cvt(const float* __restrict__ x, h8* __restrict__ xh, uint2* __restrict__ x8, int n8){
    int g = blockIdx.x*256 + threadIdx.x;
    if (g < n8){
        const f4* xp = (const f4*)(x + (size_t)g*8);
        f4 a = xp[0], b = xp[1];
        h8 o;
        o[0]=(_Float16)a[0]; o[1]=(_Float16)a[1]; o[2]=(_Float16)a[2]; o[3]=(_Float16)a[3];
        o[4]=(_Float16)b[0]; o[5]=(_Float16)b[1]; o[6]=(_Float16)b[2]; o[7]=(_Float16)b[3];
        xh[g] = o;
        int w0 = __builtin_amdgcn_cvt_pk_fp8_f32(a[0], a[1], 0, false);
        w0     = __builtin_amdgcn_cvt_pk_fp8_f32(a[2], a[3], w0, true);
        int w1 = __builtin_amdgcn_cvt_pk_fp8_f32(b[0], b[1], 0, false);
        w1     = __builtin_amdgcn_cvt_pk_fp8_f32(b[2], b[3], w1, true);
        uint2 p; p.x = (unsigned)w0; p.y = (unsigned)w1;
        x8[g] = p;
    }
}

// ---------------- weight packing: frag(kt,jt): lane holds W[kt*32+(l>>4)*8+r][jt*16+(l&15)]
__device__ inline void pack_one(const float* __restrict__ W, int C, _Float16* __restrict__ outp, int tid){
    int l = tid & 63;
    int f = tid >> 6;
    int NJT = C / 16;
    int kt = f / NJT;
    int jt = f - kt*NJT;
    int kbase = kt*32 + (l >> 4)*8;
    int col   = jt*16 + (l & 15);
    h8 o;
    #pragma unroll
    for (int r = 0; r < 8; ++r) o[r] = (_Float16)W[(kbase + r)*C + col];
    ((h8*)outp)[f*64 + l] = o;
}

__global__ void k_pack(const float* __restrict__ Wl1, const float* __restrict__ Wr1,
                       const float* __restrict__ Wl2, const float* __restrict__ Wr2,
                       _Float16* __restrict__ wl1p, _Float16* __restrict__ wr1p,
                       _Float16* __restrict__ wl2p, _Float16* __restrict__ wr2p){
    int tid = blockIdx.x*256 + threadIdx.x;
    if (tid < 2048)        pack_one(Wl1, 128, wl1p, tid);
    else if (tid < 4096)   pack_one(Wr1, 128, wr1p, tid - 2048);
    else if (tid < 5120)   pack_one(Wl2,  64, wl2p, tid - 4096);
    else if (tid < 6144)   pack_one(Wr2,  64, wr2p, tid - 5120);
}

// ---------------- aggregation 1: 16 lanes per node (lane c owns feats 8c..8c+7 via uint2), unroll-4 ----------------
__global__ void k_agg1(const int* __restrict__ row_start, const int* __restrict__ csr,
                       const uint2* __restrict__ x8, unsigned* __restrict__ mh32, int n){
    int node = (int)((blockIdx.x*(unsigned)blockDim.x + threadIdx.x) >> 4);
    int c = threadIdx.x & 15;
    if (node >= n) return;
    int base = row_start[node], end = row_start[node+1];
    int deg = end - base;
    f2 a0={0.f,0.f}, a1={0.f,0.f}, a2={0.f,0.f}, a3={0.f,0.f};
    f2 b0={0.f,0.f}, b1={0.f,0.f}, b2={0.f,0.f}, b3={0.f,0.f};
    int i = base;
    for (; i + 3 < end; i += 4){
        int e0 = csr[i], e1 = csr[i+1], e2 = csr[i+2], e3 = csr[i+3];
        uint2 v0 = x8[(size_t)e0*16 + c];
        uint2 v1 = x8[(size_t)e1*16 + c];
        uint2 v2 = x8[(size_t)e2*16 + c];
        uint2 v3 = x8[(size_t)e3*16 + c];
        a0 += __builtin_amdgcn_cvt_pk_f32_fp8(v0.x, false);
        a1 += __builtin_amdgcn_cvt_pk_f32_fp8(v0.x, true);
        a2 += __builtin_amdgcn_cvt_pk_f32_fp8(v0.y, false);
        a3 += __builtin_amdgcn_cvt_pk_f32_fp8(v0.y, true);
        b0 += __builtin_amdgcn_cvt_pk_f32_fp8(v1.x, false);
        b1 += __builtin_amdgcn_cvt_pk_f32_fp8(v1.x, true);
        b2 += __builtin_amdgcn_cvt_pk_f32_fp8(v1.y, false);
        b3 += __builtin_amdgcn_cvt_pk_f32_fp8(v1.y, true);
        a0 += __builtin_amdgcn_cvt_pk_f32_fp8(v2.x, false);
        a1 += __builtin_amdgcn_cvt_pk_f32_fp8(v2.x, true);
        a2 += __builtin_amdgcn_cvt_pk_f32_fp8(v2.y, false);
        a3 += __builtin_amdgcn_cvt_pk_f32_fp8(v2.y, true);
        b0 += __builtin_amdgcn_cvt_pk_f32_fp8(v3.x, false);
        b1 += __builtin_amdgcn_cvt_pk_f32_fp8(v3.x, true);
        b2 += __builtin_amdgcn_cvt_pk_f32_fp8(v3.y, false);
        b3 += __builtin_amdgcn_cvt_pk_f32_fp8(v3.y, true);
    }
    for (; i < end; ++i){
        int e = csr[i];
        uint2 v = x8[(size_t)e*16 + c];
        a0 += __builtin_amdgcn_cvt_pk_f32_fp8(v.x, false);
        a1 += __builtin_amdgcn_cvt_pk_f32_fp8(v.x, true);
        a2 += __builtin_amdgcn_cvt_pk_f32_fp8(v.y, false);
        a3 += __builtin_amdgcn_cvt_pk_f32_fp8(v.y, true);
    }
    a0 += b0; a1 += b1; a2 += b2; a3 += b3;
    float sc = 1.0f / (float)max(deg, 1);
    u4 o;
    o[0] = packh2(a0[0]*sc, a0[1]*sc);
    o[1] = packh2(a1[0]*sc, a1[1]*sc);
    o[2] = packh2(a2[0]*sc, a2[1]*sc);
    o[3] = packh2(a3[0]*sc, a3[1]*sc);
    *(u4*)(mh32 + (size_t)node*64 + 4*c) = o;
}

// ---------------- fused GEMM: layer-1 weights LDS-staged; H^T in-register; layer 2 fused; P out fp8 ----------------
__global__ __launch_bounds__(256, 2) void k_gemm_fused(
    const _Float16* __restrict__ A0,   // m1h [M][128] f16
    const _Float16* __restrict__ A1,   // xh  [M][128] f16
    const h8* __restrict__ B0,         // wl1p frags (2048 h8)
    const h8* __restrict__ B1,         // wr1p frags (2048 h8)
    const float* __restrict__ bias1,
    const h8* __restrict__ W2l,        // wl2p frags
    const h8* __restrict__ W2r,        // wr2p frags
    const float* __restrict__ bias2,
    unsigned* __restrict__ P8,         // [M][16] u32 (64 fp8)
    float* __restrict__ Q,             // [M][64] f32 (aliases d_out)
    int M)
{
    __shared__ h8 shB[4096];           // 64 KB: [0..2047]=wl1p, [2048..4095]=wr1p
    int tid = threadIdx.x;
    #pragma unroll
    for (int i = 0; i < 8; ++i) shB[i*256 + tid] = B0[i*256 + tid];
    #pragma unroll
    for (int i = 0; i < 8; ++i) shB[2048 + i*256 + tid] = B1[i*256 + tid];
    __syncthreads();

    int wid = tid >> 6, lane = tid & 63;
    int m0 = (blockIdx.x*4 + wid) * 16;
    if (m0 >= M) return;
    int m = lane & 15, kg = lane >> 4;
    int rowc = min(m0 + m, M-1);

    f4 acc[8];
    #pragma unroll
    for (int j = 0; j < 8; ++j) acc[j] = (f4)0.0f;

    #pragma unroll
    for (int ph = 0; ph < 2; ++ph){
        const _Float16* A = ph ? A1 : A0;
        #pragma unroll
        for (int kt = 0; kt < 4; ++kt){
            h8 nf = *(const h8*)(A + (size_t)rowc*128 + kt*32 + kg*8);
            #pragma unroll
            for (int j = 0; j < 8; ++j){
                h8 wf = shB[ph*2048 + (kt*8 + j)*64 + lane];
                acc[j] = __builtin_amdgcn_mfma_f32_16x16x32_f16(wf, nf, acc[j], 0, 0, 0);
            }
        }
    }

    unsigned hreg[16];
    #pragma unroll
    for (int j = 0; j < 8; ++j){
        f4 bb = *(const f4*)(bias1 + j*16 + kg*4);
        float v0 = acc[j][0] + bb[0]; v0 = v0 > 0.f ? v0 : 0.f;
        float v1 = acc[j][1] + bb[1]; v1 = v1 > 0.f ? v1 : 0.f;
        float v2 = acc[j][2] + bb[2]; v2 = v2 > 0.f ? v2 : 0.f;
        float v3 = acc[j][3] + bb[3]; v3 = v3 > 0.f ? v3 : 0.f;
        hreg[2*j]   = packh2(v0, v1);
        hreg[2*j+1] = packh2(v2, v3);
    }

    f4 accP[4], accQ[4];
    #pragma unroll
    for (int j = 0; j < 4; ++j){ accP[j] = (f4)0.0f; accQ[j] = (f4)0.0f; }

    int srcA = ((kg & 1) * 2) * 16 + m;
    int srcB = srcA + 16;
    bool hi = (kg >> 1) & 1;

    #pragma unroll
    for (int kt = 0; kt < 4; ++kt){
        unsigned sA0 = (unsigned)__shfl((int)hreg[4*kt+0], srcA, 64);
        unsigned sA1 = (unsigned)__shfl((int)hreg[4*kt+1], srcA, 64);
        unsigned sA2 = (unsigned)__shfl((int)hreg[4*kt+2], srcA, 64);
        unsigned sA3 = (unsigned)__shfl((int)hreg[4*kt+3], srcA, 64);
        unsigned sB0 = (unsigned)__shfl((int)hreg[4*kt+0], srcB, 64);
        unsigned sB1 = (unsigned)__shfl((int)hreg[4*kt+1], srcB, 64);
        unsigned sB2 = (unsigned)__shfl((int)hreg[4*kt+2], srcB, 64);
        unsigned sB3 = (unsigned)__shfl((int)hreg[4*kt+3], srcB, 64);
        u4 u;
        u[0] = hi ? sA2 : sA0;
        u[1] = hi ? sA3 : sA1;
        u[2] = hi ? sB2 : sB0;
        u[3] = hi ? sB3 : sB1;
        h8 hf = __builtin_bit_cast(h8, u);
        #pragma unroll
        for (int j2 = 0; j2 < 4; ++j2){
            accP[j2] = __builtin_amdgcn_mfma_f32_16x16x32_f16(W2l[(kt*4 + j2)*64 + lane], hf, accP[j2], 0, 0, 0);
            accQ[j2] = __builtin_amdgcn_mfma_f32_16x16x32_f16(W2r[(kt*4 + j2)*64 + lane], hf, accQ[j2], 0, 0, 0);
        }
    }

    int node = m0 + m;
    if (node < M){
        #pragma unroll
        for (int j2 = 0; j2 < 4; ++j2){
            int f = j2*16 + kg*4;
            int p8 = __builtin_amdgcn_cvt_pk_fp8_f32(accP[j2][0], accP[j2][1], 0, false);
            p8     = __builtin_amdgcn_cvt_pk_fp8_f32(accP[j2][2], accP[j2][3], p8, true);
            P8[(size_t)node*16 + j2*4 + kg] = (unsigned)p8;
            f4 bb2 = *(const f4*)(bias2 + f);
            f4 qv;
            qv[0] = accQ[j2][0] + bb2[0];
            qv[1] = accQ[j2][1] + bb2[1];
            qv[2] = accQ[j2][2] + bb2[2];
            qv[3] = accQ[j2][3] + bb2[3];
            *(f4*)(Q + (size_t)node*64 + f) = qv;
        }
    }
}

// ---------------- aggregation 2: out = Q + mean-gather(P8); 16 lanes per node (lane c owns feats 4c..4c+3) ----------------
__global__ void k_agg2f(const int* __restrict__ row_start, const int* __restrict__ csr,
                        const unsigned* __restrict__ p8, const float* __restrict__ Q,
                        float* __restrict__ out, int n){
    int node = (int)((blockIdx.x*(unsigned)blockDim.x + threadIdx.x) >> 4);
    int c = threadIdx.x & 15;
    if (node >= n) return;
    int base = row_start[node], end = row_start[node+1];
    int deg = end - base;
    f2 a0={0.f,0.f}, a1={0.f,0.f}, b0={0.f,0.f}, b1={0.f,0.f};
    f2 c0={0.f,0.f}, c1={0.f,0.f}, d0={0.f,0.f}, d1={0.f,0.f};
    int i = base;
    for (; i + 3 < end; i += 4){
        int e0 = csr[i], e1 = csr[i+1], e2 = csr[i+2], e3 = csr[i+3];
        unsigned v0 = p8[(size_t)e0*16 + c];
        unsigned v1 = p8[(size_t)e1*16 + c];
        unsigned v2 = p8[(size_t)e2*16 + c];
        unsigned v3 = p8[(size_t)e3*16 + c];
        a0 += __builtin_amdgcn_cvt_pk_f32_fp8(v0, false);
        a1 += __builtin_amdgcn_cvt_pk_f32_fp8(v0, true);
        b0 += __builtin_amdgcn_cvt_pk_f32_fp8(v1, false);
        b1 += __builtin_amdgcn_cvt_pk_f32_fp8(v1, true);
        c0 += __builtin_amdgcn_cvt_pk_f32_fp8(v2, false);
        c1 += __builtin_amdgcn_cvt_pk_f32_fp8(v2, true);
        d0 += __builtin_amdgcn_cvt_pk_f32_fp8(v3, false);
        d1 += __builtin_amdgcn_cvt_pk_f32_fp8(v3, true);
    }
    for (; i < end; ++i){
        int e = csr[i];
        unsigned v = p8[(size_t)e*16 + c];
        a0 += __builtin_amdgcn_cvt_pk_f32_fp8(v, false);
        a1 += __builtin_amdgcn_cvt_pk_f32_fp8(v, true);
    }
    a0 += b0 + c0 + d0;
    a1 += b1 + c1 + d1;
    float sc = 1.0f / (float)max(deg, 1);
    f4 q = *(const f4*)(Q + (size_t)node*64 + 4*c);
    f4 o;
    o[0] = a0[0]*sc + q[0];
    o[1] = a0[1]*sc + q[1];
    o[2] = a1[0]*sc + q[2];
    o[3] = a1[1]*sc + q[3];
    *(f4*)(out + (size_t)node*64 + 4*c) = o;
}

extern "C" void kernel_launch(void* const* d_in, const int* in_sizes, int n_in,
                              void* d_out, int out_size, void* d_ws, size_t ws_size,
                              hipStream_t stream) {
    const float* x   = (const float*)d_in[0];
    const int*   ei  = (const int*)d_in[1];
    const float* Wl1 = (const float*)d_in[2];
    const float* bl1 = (const float*)d_in[3];
    const float* Wr1 = (const float*)d_in[4];
    const float* Wl2 = (const float*)d_in[5];
    const float* bl2 = (const float*)d_in[6];
    const float* Wr2 = (const float*)d_in[7];

    const int N = in_sizes[0] / IN_C;
    const int E = in_sizes[1] / 2;
    const int* src = ei;
    const int* dst = ei + E;

    const int NBLK = (E + EPB - 1) / EPB;
    const int n_s  = NBUCK * NBLK;

    char* w = (char*)d_ws;
    size_t off = 0;
    auto alloc = [&](size_t bytes) -> char* {
        char* p = w + off;
        off = (off + bytes + 255) & ~(size_t)255;
        return p;
    };
    int* histT      = (int*)alloc((size_t)n_s*4);
    int* tmp        = (int*)alloc((size_t)n_s*4);
    int* bsum       = (int*)alloc(4096);
    unsigned* sorted= (unsigned*)alloc((size_t)E*4);
    int* csr        = (int*)alloc((size_t)E*4);
    int* row_start  = (int*)alloc((size_t)(N+1)*4);
    _Float16* xh    = (_Float16*)alloc((size_t)N*IN_C*2);
    unsigned* x8    = (unsigned*)alloc((size_t)N*IN_C);
    _Float16* m1h   = (_Float16*)alloc((size_t)N*IN_C*2);
    unsigned* p8    = (unsigned*)alloc((size_t)N*OUT_C);
    _Float16* wl1p  = (_Float16*)alloc(4*8*64*8*2);
    _Float16* wr1p  = (_Float16*)alloc(4*8*64*8*2);
    _Float16* wl2p  = (_Float16*)alloc(4*4*64*8*2);
    _Float16* wr2p  = (_Float16*)alloc(4*4*64*8*2);

    const int SB = (n_s + 255) / 256;

    k_hist   <<<NBLK, 256, 0, stream>>>(dst, E, histT, NBLK);
    k_scanA  <<<SB, 256, 0, stream>>>(histT, tmp, bsum, n_s);
    k_scanB  <<<1, 1024, 0, stream>>>(bsum, SB);
    k_scatter<<<NBLK, 256, 0, stream>>>(src, dst, E, tmp, bsum, NBLK, sorted);
    k_csr    <<<NBUCK, 512, 0, stream>>>(sorted, tmp, bsum, NBLK, E, N, csr, row_start);

    const int n8 = N*IN_C/8;
    k_cvt<<<(n8 + 255)/256, 256, 0, stream>>>(x, (h8*)xh, (uint2*)x8, n8);
    k_pack<<<24, 256, 0, stream>>>(Wl1, Wr1, Wl2, Wr2, wl1p, wr1p, wl2p, wr2p);

    const int AB = (N + 15) / 16;    // 16 lanes per node
    k_agg1<<<AB, 256, 0, stream>>>(row_start, csr, (const uint2*)x8, (unsigned*)m1h, N);

    float* Q = (float*)d_out;
    const int GB2 = (N + 63)/64;
    k_gemm_fused<<<GB2, 256, 0, stream>>>(m1h, xh, (const h8*)wl1p, (const h8*)wr1p, bl1,
                                          (const h8*)wl2p, (const h8*)wr2p, bl2,
                                          p8, Q, N);

    k_agg2f<<<AB, 256, 0, stream>>>(row_start, csr, p8, Q, (float*)d_out, N);
}